// Round 1
// baseline (28885.461 us; speedup 1.0000x reference)
//
#include <hip/hip_runtime.h>
#include <math.h>

#define NN 50000
#define NE 1600000
#define NG 64
#define NT 5
#define NH 64
#define NED 9
#define NIN 10
#define NOUT 3
#define EPSF 1e-6f

// ---------------- per-graph edge stats ----------------
__global__ void stats_kernel(const int* __restrict__ ei, const float* __restrict__ ea,
                             const int* __restrict__ batch,
                             float* __restrict__ ssum, float* __restrict__ ssq,
                             float* __restrict__ scnt) {
    __shared__ float lsum[NG * NED];
    __shared__ float lsq[NG * NED];
    __shared__ float lcnt[NG];
    for (int i = threadIdx.x; i < NG * NED; i += blockDim.x) { lsum[i] = 0.f; lsq[i] = 0.f; }
    for (int i = threadIdx.x; i < NG; i += blockDim.x) lcnt[i] = 0.f;
    __syncthreads();
    int stride = gridDim.x * blockDim.x;
    for (int e = blockIdx.x * blockDim.x + threadIdx.x; e < NE; e += stride) {
        int s = ei[e];
        int g = batch[s];
        atomicAdd(&lcnt[g], 1.0f);
#pragma unroll
        for (int d = 0; d < NED; ++d) {
            float a = ea[(size_t)e * NED + d];
            atomicAdd(&lsum[g * NED + d], a);
            atomicAdd(&lsq[g * NED + d], a * a);
        }
    }
    __syncthreads();
    for (int i = threadIdx.x; i < NG * NED; i += blockDim.x) {
        atomicAdd(&ssum[i], lsum[i]);
        atomicAdd(&ssq[i], lsq[i]);
    }
    for (int i = threadIdx.x; i < NG; i += blockDim.x) atomicAdd(&scnt[i], lcnt[i]);
}

__global__ void stats_fin(const float* __restrict__ ssum, const float* __restrict__ ssq,
                          const float* __restrict__ scnt,
                          float* __restrict__ mu, float* __restrict__ rstd) {
    int i = blockIdx.x * blockDim.x + threadIdx.x;
    if (i >= NG * NED) return;
    int g = i / NED;
    float c = fmaxf(scnt[g], 1.0f);
    float m = ssum[i] / c;
    float q = ssq[i] / c;
    float var = fmaxf(q - m * m, 0.f);
    mu[i] = m;
    rstd[i] = 1.0f / (sqrtf(var) + EPSF);
}

// ---------------- in-degree ----------------
__global__ void deg_kernel(const int* __restrict__ dst, float* __restrict__ deg) {
    int stride = gridDim.x * blockDim.x;
    for (int e = blockIdx.x * blockDim.x + threadIdx.x; e < NE; e += stride)
        atomicAdd(&deg[dst[e]], 1.0f);
}

// ---------------- lift MLP: v0 = relu(x@W1+b1)@W2+b2 ----------------
__global__ __launch_bounds__(256) void lift_kernel(
    const float* __restrict__ x,
    const float* __restrict__ W1, const float* __restrict__ b1,
    const float* __restrict__ W2, const float* __restrict__ b2,
    float* __restrict__ v0, float* __restrict__ v, float* __restrict__ ldy) {
    __shared__ float sW1[NIN * NH];                 // [k][j] natural
    __shared__ __align__(16) float sW2[NH][NH];     // transposed: [j][k]
    __shared__ float sb1[NH], sb2[NH];
    for (int i = threadIdx.x; i < NIN * NH; i += blockDim.x) sW1[i] = W1[i];
    for (int i = threadIdx.x; i < NH * NH; i += blockDim.x) {
        int k = i >> 6, j = i & 63;
        sW2[j][k] = W2[i];
    }
    for (int i = threadIdx.x; i < NH; i += blockDim.x) { sb1[i] = b1[i]; sb2[i] = b2[i]; }
    __syncthreads();
    int stride = gridDim.x * blockDim.x;
    for (int n = blockIdx.x * blockDim.x + threadIdx.x; n < NN; n += stride) {
        float xr[NIN];
#pragma unroll
        for (int k = 0; k < NIN; ++k) xr[k] = x[(size_t)n * NIN + k];
        ldy[n] = xr[4];
        float h[NH];
#pragma unroll
        for (int j = 0; j < NH; ++j) {
            float acc = sb1[j];
#pragma unroll
            for (int k = 0; k < NIN; ++k) acc += xr[k] * sW1[k * NH + j];
            h[j] = fmaxf(acc, 0.f);
        }
#pragma unroll
        for (int j = 0; j < NH; ++j) {
            float acc = sb2[j];
#pragma unroll
            for (int k = 0; k < NH; k += 4) {
                float4 w = *(const float4*)&sW2[j][k];
                acc += h[k] * w.x + h[k + 1] * w.y + h[k + 2] * w.z + h[k + 3] * w.w;
            }
            v0[(size_t)n * NH + j] = acc;
            v[(size_t)n * NH + j] = acc;
        }
    }
}

// ---------------- edge message MLP + scatter ----------------
__global__ __launch_bounds__(256) void msg_kernel(
    const int* __restrict__ ei, const float* __restrict__ ea, const int* __restrict__ batch,
    const float* __restrict__ W0, const float* __restrict__ b0,
    const float* __restrict__ W1, const float* __restrict__ b1,
    const float* __restrict__ W2, const float* __restrict__ b2,
    const float* __restrict__ mu, const float* __restrict__ rstd,
    const float* __restrict__ v, float* __restrict__ agg) {
    __shared__ __align__(16) float sW0[NH][76];   // [j][k], k=0..72 data, 73..75 zero pad
    __shared__ __align__(16) float sW1[NH][NH];   // [j][k]
    __shared__ __align__(16) float sW2[NH][NH];   // [j][k]
    __shared__ float sb0[NH], sb1[NH], sb2[NH];
    __shared__ float smu[NG * NED], srstd[NG * NED];

    for (int i = threadIdx.x; i < (NH + NED) * NH; i += blockDim.x) {
        int k = i >> 6, j = i & 63;
        sW0[j][k] = W0[i];
    }
    for (int i = threadIdx.x; i < 3 * NH; i += blockDim.x) {
        int j = i / 3, p = i - j * 3;
        sW0[j][73 + p] = 0.f;
    }
    for (int i = threadIdx.x; i < NH * NH; i += blockDim.x) {
        int k = i >> 6, j = i & 63;
        sW1[j][k] = W1[i];
        sW2[j][k] = W2[i];
    }
    for (int i = threadIdx.x; i < NH; i += blockDim.x) { sb0[i] = b0[i]; sb1[i] = b1[i]; sb2[i] = b2[i]; }
    for (int i = threadIdx.x; i < NG * NED; i += blockDim.x) { smu[i] = mu[i]; srstd[i] = rstd[i]; }
    __syncthreads();

    int stride = gridDim.x * blockDim.x;
    for (int e = blockIdx.x * blockDim.x + threadIdx.x; e < NE; e += stride) {
        int s = ei[e];
        int dn = ei[NE + e];
        int g = batch[s];
        float in[76];
        const float4* vs = (const float4*)(v + (size_t)s * NH);
#pragma unroll
        for (int q = 0; q < NH / 4; ++q) {
            float4 f = vs[q];
            in[4 * q + 0] = f.x; in[4 * q + 1] = f.y; in[4 * q + 2] = f.z; in[4 * q + 3] = f.w;
        }
#pragma unroll
        for (int d = 0; d < NED; ++d)
            in[NH + d] = (ea[(size_t)e * NED + d] - smu[g * NED + d]) * srstd[g * NED + d];
        in[73] = 0.f; in[74] = 0.f; in[75] = 0.f;

        float h0[NH];
#pragma unroll
        for (int j = 0; j < NH; ++j) {
            float acc = sb0[j];
#pragma unroll
            for (int k = 0; k < 76; k += 4) {
                float4 w = *(const float4*)&sW0[j][k];
                acc += in[k] * w.x + in[k + 1] * w.y + in[k + 2] * w.z + in[k + 3] * w.w;
            }
            h0[j] = fmaxf(acc, 0.f);
        }
        float h1[NH];
#pragma unroll
        for (int j = 0; j < NH; ++j) {
            float acc = sb1[j];
#pragma unroll
            for (int k = 0; k < NH; k += 4) {
                float4 w = *(const float4*)&sW1[j][k];
                acc += h0[k] * w.x + h0[k + 1] * w.y + h0[k + 2] * w.z + h0[k + 3] * w.w;
            }
            h1[j] = fmaxf(acc, 0.f);
        }
        float* arow = agg + (size_t)dn * NH;
#pragma unroll
        for (int j = 0; j < NH; ++j) {
            float acc = sb2[j];
#pragma unroll
            for (int k = 0; k < NH; k += 4) {
                float4 w = *(const float4*)&sW2[j][k];
                acc += h1[k] * w.x + h1[k + 1] * w.y + h1[k + 2] * w.z + h1[k + 3] * w.w;
            }
            atomicAdd(&arow[j], acc);
        }
    }
}

// ---------------- node update ----------------
__global__ __launch_bounds__(256) void update_kernel(
    const float* __restrict__ Wself, const float* __restrict__ bself,
    const float* __restrict__ gWt, const float* __restrict__ gbt,
    const float* __restrict__ v0, const float* __restrict__ ldy,
    const float* __restrict__ deg, const float* __restrict__ agg,
    float* __restrict__ v) {
    __shared__ __align__(16) float sW[NH][NH];   // [j][k]
    __shared__ float sb[NH], sgw[NH], sgb[NH];
    for (int i = threadIdx.x; i < NH * NH; i += blockDim.x) {
        int k = i >> 6, j = i & 63;
        sW[j][k] = Wself[i];
    }
    for (int i = threadIdx.x; i < NH; i += blockDim.x) { sb[i] = bself[i]; sgw[i] = gWt[i]; sgb[i] = gbt[i]; }
    __syncthreads();
    int stride = gridDim.x * blockDim.x;
    for (int n = blockIdx.x * blockDim.x + threadIdx.x; n < NN; n += stride) {
        float vr[NH];
        const float4* vp = (const float4*)(v + (size_t)n * NH);
#pragma unroll
        for (int q = 0; q < NH / 4; ++q) {
            float4 f = vp[q];
            vr[4 * q + 0] = f.x; vr[4 * q + 1] = f.y; vr[4 * q + 2] = f.z; vr[4 * q + 3] = f.w;
        }
        float dninv = 1.f / fmaxf(deg[n], 1.f);
        float ld = ldy[n];
        const float* ar = agg + (size_t)n * NH;
        const float* v0r = v0 + (size_t)n * NH;
        float outv[NH];
#pragma unroll
        for (int j = 0; j < NH; ++j) {
            float acc = sb[j];
#pragma unroll
            for (int k = 0; k < NH; k += 4) {
                float4 w = *(const float4*)&sW[j][k];
                acc += vr[k] * w.x + vr[k + 1] * w.y + vr[k + 2] * w.z + vr[k + 3] * w.w;
            }
            float z = ld * sgw[j] + sgb[j];
            float gate = 1.f / (1.f + expf(-z));
            outv[j] = fmaxf(acc + ar[j] * dninv + v0r[j], 0.f) * gate;
        }
        float4* vo = (float4*)(v + (size_t)n * NH);
#pragma unroll
        for (int q = 0; q < NH / 4; ++q) {
            float4 f;
            f.x = outv[4 * q + 0]; f.y = outv[4 * q + 1]; f.z = outv[4 * q + 2]; f.w = outv[4 * q + 3];
            vo[q] = f;
        }
    }
}

// ---------------- projection ----------------
__global__ __launch_bounds__(256) void proj_kernel(
    const float* __restrict__ v,
    const float* __restrict__ pW1, const float* __restrict__ pb1,
    const float* __restrict__ pW2, const float* __restrict__ pb2,
    float* __restrict__ out) {
    __shared__ __align__(16) float sW1[NH][NH];   // [j][k]
    __shared__ float sb1[NH];
    __shared__ float sW2[NH * NOUT];
    __shared__ float sb2[NOUT];
    for (int i = threadIdx.x; i < NH * NH; i += blockDim.x) {
        int k = i >> 6, j = i & 63;
        sW1[j][k] = pW1[i];
    }
    for (int i = threadIdx.x; i < NH; i += blockDim.x) sb1[i] = pb1[i];
    for (int i = threadIdx.x; i < NH * NOUT; i += blockDim.x) sW2[i] = pW2[i];
    for (int i = threadIdx.x; i < NOUT; i += blockDim.x) sb2[i] = pb2[i];
    __syncthreads();
    int stride = gridDim.x * blockDim.x;
    for (int n = blockIdx.x * blockDim.x + threadIdx.x; n < NN; n += stride) {
        float vr[NH];
        const float4* vp = (const float4*)(v + (size_t)n * NH);
#pragma unroll
        for (int q = 0; q < NH / 4; ++q) {
            float4 f = vp[q];
            vr[4 * q + 0] = f.x; vr[4 * q + 1] = f.y; vr[4 * q + 2] = f.z; vr[4 * q + 3] = f.w;
        }
        float o0 = sb2[0], o1 = sb2[1], o2 = sb2[2];
#pragma unroll
        for (int j = 0; j < NH; ++j) {
            float acc = sb1[j];
#pragma unroll
            for (int k = 0; k < NH; k += 4) {
                float4 w = *(const float4*)&sW1[j][k];
                acc += vr[k] * w.x + vr[k + 1] * w.y + vr[k + 2] * w.z + vr[k + 3] * w.w;
            }
            float h = fmaxf(acc, 0.f);
            o0 += h * sW2[j * NOUT + 0];
            o1 += h * sW2[j * NOUT + 1];
            o2 += h * sW2[j * NOUT + 2];
        }
        out[(size_t)n * NOUT + 0] = o0;
        out[(size_t)n * NOUT + 1] = o1;
        out[(size_t)n * NOUT + 2] = o2;
    }
}

extern "C" void kernel_launch(void* const* d_in, const int* in_sizes, int n_in,
                              void* d_out, int out_size, void* d_ws, size_t ws_size,
                              hipStream_t stream) {
    (void)in_sizes; (void)n_in; (void)out_size; (void)ws_size;
    const float* x     = (const float*)d_in[0];
    const int*   ei    = (const int*)d_in[1];
    const float* ea    = (const float*)d_in[2];
    const int*   batch = (const int*)d_in[3];
    const float* lW1   = (const float*)d_in[4];
    const float* lb1   = (const float*)d_in[5];
    const float* lW2   = (const float*)d_in[6];
    const float* lb2   = (const float*)d_in[7];
    const float* Wself = (const float*)d_in[8];
    const float* bself = (const float*)d_in[9];
    const float* mW0   = (const float*)d_in[10];
    const float* mb0   = (const float*)d_in[11];
    const float* mW1   = (const float*)d_in[12];
    const float* mb1   = (const float*)d_in[13];
    const float* mW2   = (const float*)d_in[14];
    const float* mb2   = (const float*)d_in[15];
    const float* gW    = (const float*)d_in[16];
    const float* gb    = (const float*)d_in[17];
    const float* pW1   = (const float*)d_in[18];
    const float* pb1   = (const float*)d_in[19];
    const float* pW2   = (const float*)d_in[20];
    const float* pb2   = (const float*)d_in[21];
    float* out = (float*)d_out;
    float* ws  = (float*)d_ws;

    float* agg  = ws;                          // NN*NH
    float* deg  = agg + (size_t)NN * NH;       // NN
    float* ssum = deg + NN;                    // NG*NED
    float* ssq  = ssum + NG * NED;             // NG*NED
    float* scnt = ssq + NG * NED;              // NG
    float* v0   = scnt + NG;                   // NN*NH
    float* v    = v0 + (size_t)NN * NH;        // NN*NH
    float* ldy  = v + (size_t)NN * NH;         // NN
    float* mu   = ldy + NN;                    // NG*NED
    float* rstd = mu + NG * NED;               // NG*NED

    // zero deg + stats accumulators (contiguous)
    hipMemsetAsync(deg, 0, (size_t)(NN + 2 * NG * NED + NG) * sizeof(float), stream);

    stats_kernel<<<256, 256, 0, stream>>>(ei, ea, batch, ssum, ssq, scnt);
    stats_fin<<<3, 256, 0, stream>>>(ssum, ssq, scnt, mu, rstd);
    deg_kernel<<<2048, 256, 0, stream>>>(ei + NE, deg);
    lift_kernel<<<200, 256, 0, stream>>>(x, lW1, lb1, lW2, lb2, v0, v, ldy);

    for (int t = 0; t < NT; ++t) {
        hipMemsetAsync(agg, 0, (size_t)NN * NH * sizeof(float), stream);
        msg_kernel<<<1024, 256, 0, stream>>>(
            ei, ea, batch,
            mW0 + (size_t)t * (NH + NED) * NH, mb0 + (size_t)t * NH,
            mW1 + (size_t)t * NH * NH, mb1 + (size_t)t * NH,
            mW2 + (size_t)t * NH * NH, mb2 + (size_t)t * NH,
            mu, rstd, v, agg);
        update_kernel<<<200, 256, 0, stream>>>(
            Wself + (size_t)t * NH * NH, bself + (size_t)t * NH,
            gW + (size_t)t * NH, gb + (size_t)t * NH,
            v0, ldy, deg, agg, v);
    }
    proj_kernel<<<200, 256, 0, stream>>>(v, pW1, pb1, pW2, pb2, out);
}

// Round 2
// 4190.241 us; speedup vs baseline: 6.8935x; 6.8935x over previous
//
#include <hip/hip_runtime.h>
#include <math.h>

#define NN 50000
#define NE 1600000
#define NG 64
#define NT 5
#define NH 64
#define NED 9
#define NIN 10
#define NOUT 3
#define EPSF 1e-6f

// ---------------- per-graph edge stats ----------------
__global__ void stats_kernel(const int* __restrict__ ei, const float* __restrict__ ea,
                             const int* __restrict__ batch,
                             float* __restrict__ ssum, float* __restrict__ ssq,
                             float* __restrict__ scnt) {
    __shared__ float lsum[NG * NED];
    __shared__ float lsq[NG * NED];
    __shared__ float lcnt[NG];
    for (int i = threadIdx.x; i < NG * NED; i += blockDim.x) { lsum[i] = 0.f; lsq[i] = 0.f; }
    for (int i = threadIdx.x; i < NG; i += blockDim.x) lcnt[i] = 0.f;
    __syncthreads();
    int stride = gridDim.x * blockDim.x;
    for (int e = blockIdx.x * blockDim.x + threadIdx.x; e < NE; e += stride) {
        int s = ei[e];
        int g = batch[s];
        atomicAdd(&lcnt[g], 1.0f);
#pragma unroll
        for (int d = 0; d < NED; ++d) {
            float a = ea[(size_t)e * NED + d];
            atomicAdd(&lsum[g * NED + d], a);
            atomicAdd(&lsq[g * NED + d], a * a);
        }
    }
    __syncthreads();
    for (int i = threadIdx.x; i < NG * NED; i += blockDim.x) {
        atomicAdd(&ssum[i], lsum[i]);
        atomicAdd(&ssq[i], lsq[i]);
    }
    for (int i = threadIdx.x; i < NG; i += blockDim.x) atomicAdd(&scnt[i], lcnt[i]);
}

__global__ void stats_fin(const float* __restrict__ ssum, const float* __restrict__ ssq,
                          const float* __restrict__ scnt,
                          float* __restrict__ mu, float* __restrict__ rstd) {
    int i = blockIdx.x * blockDim.x + threadIdx.x;
    if (i >= NG * NED) return;
    int g = i / NED;
    float c = fmaxf(scnt[g], 1.0f);
    float m = ssum[i] / c;
    float q = ssq[i] / c;
    float var = fmaxf(q - m * m, 0.f);
    mu[i] = m;
    rstd[i] = 1.0f / (sqrtf(var) + EPSF);
}

// ---------------- in-degree ----------------
__global__ void deg_kernel(const int* __restrict__ dst, float* __restrict__ deg) {
    int stride = gridDim.x * blockDim.x;
    for (int e = blockIdx.x * blockDim.x + threadIdx.x; e < NE; e += stride)
        atomicAdd(&deg[dst[e]], 1.0f);
}

// ---------------- lift MLP ----------------
__global__ __launch_bounds__(256) void lift_kernel(
    const float* __restrict__ x,
    const float* __restrict__ W1, const float* __restrict__ b1,
    const float* __restrict__ W2, const float* __restrict__ b2,
    float* __restrict__ v0, float* __restrict__ v, float* __restrict__ ldy) {
    __shared__ float sW1[NIN * NH];
    __shared__ __align__(16) float sW2[NH][NH];     // transposed: [j][k]
    __shared__ float sb1[NH], sb2[NH];
    for (int i = threadIdx.x; i < NIN * NH; i += blockDim.x) sW1[i] = W1[i];
    for (int i = threadIdx.x; i < NH * NH; i += blockDim.x) {
        int k = i >> 6, j = i & 63;
        sW2[j][k] = W2[i];
    }
    for (int i = threadIdx.x; i < NH; i += blockDim.x) { sb1[i] = b1[i]; sb2[i] = b2[i]; }
    __syncthreads();
    int stride = gridDim.x * blockDim.x;
    for (int n = blockIdx.x * blockDim.x + threadIdx.x; n < NN; n += stride) {
        float xr[NIN];
#pragma unroll
        for (int k = 0; k < NIN; ++k) xr[k] = x[(size_t)n * NIN + k];
        ldy[n] = xr[4];
        float h[NH];
#pragma unroll
        for (int j = 0; j < NH; ++j) {
            float acc = sb1[j];
#pragma unroll
            for (int k = 0; k < NIN; ++k) acc += xr[k] * sW1[k * NH + j];
            h[j] = fmaxf(acc, 0.f);
        }
#pragma unroll
        for (int j = 0; j < NH; ++j) {
            float acc = sb2[j];
#pragma unroll
            for (int k = 0; k < NH; k += 4) {
                float4 w = *(const float4*)&sW2[j][k];
                acc += h[k] * w.x + h[k + 1] * w.y + h[k + 2] * w.z + h[k + 3] * w.w;
            }
            v0[(size_t)n * NH + j] = acc;
            v[(size_t)n * NH + j] = acc;
        }
    }
}

// ---------------- edge message: register-tiled GEMM ----------------
// Block = 64 edges x 64 outputs, 256 threads, 4x4 micro-tile per thread.
// LDS: A[76][68] activations ([k][edge]), Hh[64][68], Wb[76][64] weights ([k][j]).
__device__ __forceinline__ void gemm_acc(const float* __restrict__ Ab,
                                         const float* __restrict__ Wb,
                                         int K, int te, int tj, float acc[4][4]) {
#pragma unroll 4
    for (int k = 0; k < K; ++k) {
        float4 a = *(const float4*)(Ab + k * 68 + (te << 2));
        float4 b = *(const float4*)(Wb + (k << 6) + (tj << 2));
        acc[0][0] = fmaf(a.x, b.x, acc[0][0]);
        acc[0][1] = fmaf(a.x, b.y, acc[0][1]);
        acc[0][2] = fmaf(a.x, b.z, acc[0][2]);
        acc[0][3] = fmaf(a.x, b.w, acc[0][3]);
        acc[1][0] = fmaf(a.y, b.x, acc[1][0]);
        acc[1][1] = fmaf(a.y, b.y, acc[1][1]);
        acc[1][2] = fmaf(a.y, b.z, acc[1][2]);
        acc[1][3] = fmaf(a.y, b.w, acc[1][3]);
        acc[2][0] = fmaf(a.z, b.x, acc[2][0]);
        acc[2][1] = fmaf(a.z, b.y, acc[2][1]);
        acc[2][2] = fmaf(a.z, b.z, acc[2][2]);
        acc[2][3] = fmaf(a.z, b.w, acc[2][3]);
        acc[3][0] = fmaf(a.w, b.x, acc[3][0]);
        acc[3][1] = fmaf(a.w, b.y, acc[3][1]);
        acc[3][2] = fmaf(a.w, b.z, acc[3][2]);
        acc[3][3] = fmaf(a.w, b.w, acc[3][3]);
    }
}

__global__ __launch_bounds__(256, 2) void msg2_kernel(
    const int* __restrict__ ei, const float* __restrict__ ea, const int* __restrict__ batch,
    const float* __restrict__ W0, const float* __restrict__ b0,
    const float* __restrict__ W1, const float* __restrict__ b1,
    const float* __restrict__ W2, const float* __restrict__ b2,
    const float* __restrict__ mu, const float* __restrict__ rstd,
    const float* __restrict__ v, float* __restrict__ agg) {
    __shared__ __align__(16) float A[76][68];
    __shared__ __align__(16) float Hh[64][68];
    __shared__ __align__(16) float Wb[76][64];
    __shared__ int sSrc[64], sDst[64], sG[64];
    __shared__ float sb[64];

    const int tid = threadIdx.x;
    const int base = blockIdx.x * 64;
    const int te = tid >> 4, tj = tid & 15;

    // --- stage indices ---
    if (tid < 64) {
        int s = ei[base + tid];
        sSrc[tid] = s;
        sDst[tid] = ei[NE + base + tid];
        sG[tid] = batch[s];
    }
    // --- stage W0 ([k][j], zero-pad rows 73..75) + b0 ---
    for (int i4 = tid; i4 < 76 * 16; i4 += 256) {
        int k = i4 >> 4, c4 = i4 & 15;
        float4 w = (k < 73) ? *(const float4*)(W0 + (size_t)k * 64 + c4 * 4)
                            : make_float4(0.f, 0.f, 0.f, 0.f);
        *(float4*)&Wb[k][c4 * 4] = w;
    }
    if (tid < 64) sb[tid] = b0[tid];
    __syncthreads();

    // --- stage A: v[src] transposed to [k][edge] ---
    {
        int r = tid >> 2;                 // 64 rows
        int kb = (tid & 3) << 4;          // 4 chunks of 16 k
        const float4* vrow = (const float4*)(v + (size_t)sSrc[r] * NH + kb);
#pragma unroll
        for (int q = 0; q < 4; ++q) {
            float4 f = vrow[q];
            int k = kb + q * 4;
            A[k + 0][r] = f.x;
            A[k + 1][r] = f.y;
            A[k + 2][r] = f.z;
            A[k + 3][r] = f.w;
        }
    }
    // --- stage A: normalized edge_attr rows 64..72, zeros 73..75 ---
    if (tid < 64) {
        int e = base + tid;
        int g = sG[tid];
#pragma unroll
        for (int d = 0; d < NED; ++d)
            A[64 + d][tid] = (ea[(size_t)e * NED + d] - mu[g * NED + d]) * rstd[g * NED + d];
        A[73][tid] = 0.f;
        A[74][tid] = 0.f;
        A[75][tid] = 0.f;
    }
    __syncthreads();

    // --- layer 0: K=76 ---
    float acc[4][4];
    {
        float bj0 = sb[tj * 4 + 0], bj1 = sb[tj * 4 + 1], bj2 = sb[tj * 4 + 2], bj3 = sb[tj * 4 + 3];
#pragma unroll
        for (int ee = 0; ee < 4; ++ee) {
            acc[ee][0] = bj0; acc[ee][1] = bj1; acc[ee][2] = bj2; acc[ee][3] = bj3;
        }
    }
    gemm_acc(&A[0][0], &Wb[0][0], 76, te, tj, acc);
    __syncthreads();

    // --- h0 -> Hh[j][e] (relu), load W1 + b1 ---
#pragma unroll
    for (int jj = 0; jj < 4; ++jj)
#pragma unroll
        for (int ee = 0; ee < 4; ++ee)
            Hh[tj * 4 + jj][te * 4 + ee] = fmaxf(acc[ee][jj], 0.f);
    for (int i4 = tid; i4 < 64 * 16; i4 += 256) {
        int k = i4 >> 4, c4 = i4 & 15;
        *(float4*)&Wb[k][c4 * 4] = *(const float4*)(W1 + (size_t)k * 64 + c4 * 4);
    }
    if (tid < 64) sb[tid] = b1[tid];
    __syncthreads();

    // --- layer 1: K=64 ---
    {
        float bj0 = sb[tj * 4 + 0], bj1 = sb[tj * 4 + 1], bj2 = sb[tj * 4 + 2], bj3 = sb[tj * 4 + 3];
#pragma unroll
        for (int ee = 0; ee < 4; ++ee) {
            acc[ee][0] = bj0; acc[ee][1] = bj1; acc[ee][2] = bj2; acc[ee][3] = bj3;
        }
    }
    gemm_acc(&Hh[0][0], &Wb[0][0], 64, te, tj, acc);
    __syncthreads();

    // --- h1 -> A[j][e] (relu), load W2 + b2 ---
#pragma unroll
    for (int jj = 0; jj < 4; ++jj)
#pragma unroll
        for (int ee = 0; ee < 4; ++ee)
            A[tj * 4 + jj][te * 4 + ee] = fmaxf(acc[ee][jj], 0.f);
    for (int i4 = tid; i4 < 64 * 16; i4 += 256) {
        int k = i4 >> 4, c4 = i4 & 15;
        *(float4*)&Wb[k][c4 * 4] = *(const float4*)(W2 + (size_t)k * 64 + c4 * 4);
    }
    if (tid < 64) sb[tid] = b2[tid];
    __syncthreads();

    // --- layer 2: K=64 (no relu) ---
    {
        float bj0 = sb[tj * 4 + 0], bj1 = sb[tj * 4 + 1], bj2 = sb[tj * 4 + 2], bj3 = sb[tj * 4 + 3];
#pragma unroll
        for (int ee = 0; ee < 4; ++ee) {
            acc[ee][0] = bj0; acc[ee][1] = bj1; acc[ee][2] = bj2; acc[ee][3] = bj3;
        }
    }
    gemm_acc(&A[0][0], &Wb[0][0], 64, te, tj, acc);

    // --- m -> Hh[e][j] for coalesced scatter ---
#pragma unroll
    for (int ee = 0; ee < 4; ++ee) {
        float4 m4 = make_float4(acc[ee][0], acc[ee][1], acc[ee][2], acc[ee][3]);
        *(float4*)&Hh[te * 4 + ee][tj * 4] = m4;
    }
    __syncthreads();

    // --- coalesced atomic scatter: one 256B row per edge ---
    {
        int wq = tid >> 6, lane = tid & 63;
#pragma unroll
        for (int r8 = 0; r8 < 16; ++r8) {
            int r = wq * 16 + r8;
            atomicAdd(&agg[(size_t)sDst[r] * NH + lane], Hh[r][lane]);
        }
    }
}

// ---------------- node update ----------------
__global__ __launch_bounds__(256) void update_kernel(
    const float* __restrict__ Wself, const float* __restrict__ bself,
    const float* __restrict__ gWt, const float* __restrict__ gbt,
    const float* __restrict__ v0, const float* __restrict__ ldy,
    const float* __restrict__ deg, const float* __restrict__ agg,
    float* __restrict__ v) {
    __shared__ __align__(16) float sW[NH][NH];   // [j][k]
    __shared__ float sb[NH], sgw[NH], sgb[NH];
    for (int i = threadIdx.x; i < NH * NH; i += blockDim.x) {
        int k = i >> 6, j = i & 63;
        sW[j][k] = Wself[i];
    }
    for (int i = threadIdx.x; i < NH; i += blockDim.x) { sb[i] = bself[i]; sgw[i] = gWt[i]; sgb[i] = gbt[i]; }
    __syncthreads();
    int stride = gridDim.x * blockDim.x;
    for (int n = blockIdx.x * blockDim.x + threadIdx.x; n < NN; n += stride) {
        float vr[NH];
        const float4* vp = (const float4*)(v + (size_t)n * NH);
#pragma unroll
        for (int q = 0; q < NH / 4; ++q) {
            float4 f = vp[q];
            vr[4 * q + 0] = f.x; vr[4 * q + 1] = f.y; vr[4 * q + 2] = f.z; vr[4 * q + 3] = f.w;
        }
        float dninv = 1.f / fmaxf(deg[n], 1.f);
        float ld = ldy[n];
        const float* ar = agg + (size_t)n * NH;
        const float* v0r = v0 + (size_t)n * NH;
        float outv[NH];
#pragma unroll
        for (int j = 0; j < NH; ++j) {
            float acc = sb[j];
#pragma unroll
            for (int k = 0; k < NH; k += 4) {
                float4 w = *(const float4*)&sW[j][k];
                acc += vr[k] * w.x + vr[k + 1] * w.y + vr[k + 2] * w.z + vr[k + 3] * w.w;
            }
            float z = ld * sgw[j] + sgb[j];
            float gate = 1.f / (1.f + expf(-z));
            outv[j] = fmaxf(acc + ar[j] * dninv + v0r[j], 0.f) * gate;
        }
        float4* vo = (float4*)(v + (size_t)n * NH);
#pragma unroll
        for (int q = 0; q < NH / 4; ++q) {
            float4 f;
            f.x = outv[4 * q + 0]; f.y = outv[4 * q + 1]; f.z = outv[4 * q + 2]; f.w = outv[4 * q + 3];
            vo[q] = f;
        }
    }
}

// ---------------- projection ----------------
__global__ __launch_bounds__(256) void proj_kernel(
    const float* __restrict__ v,
    const float* __restrict__ pW1, const float* __restrict__ pb1,
    const float* __restrict__ pW2, const float* __restrict__ pb2,
    float* __restrict__ out) {
    __shared__ __align__(16) float sW1[NH][NH];   // [j][k]
    __shared__ float sb1[NH];
    __shared__ float sW2[NH * NOUT];
    __shared__ float sb2[NOUT];
    for (int i = threadIdx.x; i < NH * NH; i += blockDim.x) {
        int k = i >> 6, j = i & 63;
        sW1[j][k] = pW1[i];
    }
    for (int i = threadIdx.x; i < NH; i += blockDim.x) sb1[i] = pb1[i];
    for (int i = threadIdx.x; i < NH * NOUT; i += blockDim.x) sW2[i] = pW2[i];
    for (int i = threadIdx.x; i < NOUT; i += blockDim.x) sb2[i] = pb2[i];
    __syncthreads();
    int stride = gridDim.x * blockDim.x;
    for (int n = blockIdx.x * blockDim.x + threadIdx.x; n < NN; n += stride) {
        float vr[NH];
        const float4* vp = (const float4*)(v + (size_t)n * NH);
#pragma unroll
        for (int q = 0; q < NH / 4; ++q) {
            float4 f = vp[q];
            vr[4 * q + 0] = f.x; vr[4 * q + 1] = f.y; vr[4 * q + 2] = f.z; vr[4 * q + 3] = f.w;
        }
        float o0 = sb2[0], o1 = sb2[1], o2 = sb2[2];
#pragma unroll
        for (int j = 0; j < NH; ++j) {
            float acc = sb1[j];
#pragma unroll
            for (int k = 0; k < NH; k += 4) {
                float4 w = *(const float4*)&sW1[j][k];
                acc += vr[k] * w.x + vr[k + 1] * w.y + vr[k + 2] * w.z + vr[k + 3] * w.w;
            }
            float h = fmaxf(acc, 0.f);
            o0 += h * sW2[j * NOUT + 0];
            o1 += h * sW2[j * NOUT + 1];
            o2 += h * sW2[j * NOUT + 2];
        }
        out[(size_t)n * NOUT + 0] = o0;
        out[(size_t)n * NOUT + 1] = o1;
        out[(size_t)n * NOUT + 2] = o2;
    }
}

extern "C" void kernel_launch(void* const* d_in, const int* in_sizes, int n_in,
                              void* d_out, int out_size, void* d_ws, size_t ws_size,
                              hipStream_t stream) {
    (void)in_sizes; (void)n_in; (void)out_size; (void)ws_size;
    const float* x     = (const float*)d_in[0];
    const int*   ei    = (const int*)d_in[1];
    const float* ea    = (const float*)d_in[2];
    const int*   batch = (const int*)d_in[3];
    const float* lW1   = (const float*)d_in[4];
    const float* lb1   = (const float*)d_in[5];
    const float* lW2   = (const float*)d_in[6];
    const float* lb2   = (const float*)d_in[7];
    const float* Wself = (const float*)d_in[8];
    const float* bself = (const float*)d_in[9];
    const float* mW0   = (const float*)d_in[10];
    const float* mb0   = (const float*)d_in[11];
    const float* mW1   = (const float*)d_in[12];
    const float* mb1   = (const float*)d_in[13];
    const float* mW2   = (const float*)d_in[14];
    const float* mb2   = (const float*)d_in[15];
    const float* gW    = (const float*)d_in[16];
    const float* gb    = (const float*)d_in[17];
    const float* pW1   = (const float*)d_in[18];
    const float* pb1   = (const float*)d_in[19];
    const float* pW2   = (const float*)d_in[20];
    const float* pb2   = (const float*)d_in[21];
    float* out = (float*)d_out;
    float* ws  = (float*)d_ws;

    float* agg  = ws;                          // NN*NH
    float* deg  = agg + (size_t)NN * NH;       // NN
    float* ssum = deg + NN;                    // NG*NED
    float* ssq  = ssum + NG * NED;             // NG*NED
    float* scnt = ssq + NG * NED;              // NG
    float* v0   = scnt + NG;                   // NN*NH
    float* v    = v0 + (size_t)NN * NH;        // NN*NH
    float* ldy  = v + (size_t)NN * NH;         // NN
    float* mu   = ldy + NN;                    // NG*NED
    float* rstd = mu + NG * NED;               // NG*NED

    hipMemsetAsync(deg, 0, (size_t)(NN + 2 * NG * NED + NG) * sizeof(float), stream);

    stats_kernel<<<256, 256, 0, stream>>>(ei, ea, batch, ssum, ssq, scnt);
    stats_fin<<<3, 256, 0, stream>>>(ssum, ssq, scnt, mu, rstd);
    deg_kernel<<<2048, 256, 0, stream>>>(ei + NE, deg);
    lift_kernel<<<200, 256, 0, stream>>>(x, lW1, lb1, lW2, lb2, v0, v, ldy);

    for (int t = 0; t < NT; ++t) {
        hipMemsetAsync(agg, 0, (size_t)NN * NH * sizeof(float), stream);
        msg2_kernel<<<NE / 64, 256, 0, stream>>>(
            ei, ea, batch,
            mW0 + (size_t)t * (NH + NED) * NH, mb0 + (size_t)t * NH,
            mW1 + (size_t)t * NH * NH, mb1 + (size_t)t * NH,
            mW2 + (size_t)t * NH * NH, mb2 + (size_t)t * NH,
            mu, rstd, v, agg);
        update_kernel<<<200, 256, 0, stream>>>(
            Wself + (size_t)t * NH * NH, bself + (size_t)t * NH,
            gW + (size_t)t * NH, gb + (size_t)t * NH,
            v0, ldy, deg, agg, v);
    }
    proj_kernel<<<200, 256, 0, stream>>>(v, pW1, pb1, pW2, pb2, out);
}

// Round 3
// 3461.889 us; speedup vs baseline: 8.3438x; 1.2104x over previous
//
#include <hip/hip_runtime.h>
#include <math.h>

#define NN 50000
#define NE 1600000
#define NG 64
#define NT 5
#define NH 64
#define NED 9
#define NIN 10
#define NOUT 3
#define EPSF 1e-6f

// ---------------- per-graph edge stats (wave-uniform fast path) ----------------
__global__ void stats_kernel(const int* __restrict__ ei, const float* __restrict__ ea,
                             const int* __restrict__ batch,
                             float* __restrict__ ssum, float* __restrict__ ssq,
                             float* __restrict__ scnt) {
    __shared__ float lsum[NG * NED];
    __shared__ float lsq[NG * NED];
    __shared__ float lcnt[NG];
    for (int i = threadIdx.x; i < NG * NED; i += blockDim.x) { lsum[i] = 0.f; lsq[i] = 0.f; }
    for (int i = threadIdx.x; i < NG; i += blockDim.x) lcnt[i] = 0.f;
    __syncthreads();
    int lane = threadIdx.x & 63;
    int stride = gridDim.x * blockDim.x;
    for (int e = blockIdx.x * blockDim.x + threadIdx.x; e < NE; e += stride) {
        int s = ei[e];
        int g = batch[s];
        float a[NED];
#pragma unroll
        for (int d = 0; d < NED; ++d) a[d] = ea[(size_t)e * NED + d];
        int g0 = __builtin_amdgcn_readfirstlane(g);
        if (__all(g == g0)) {
            float sv[NED], qv[NED];
#pragma unroll
            for (int d = 0; d < NED; ++d) { sv[d] = a[d]; qv[d] = a[d] * a[d]; }
#pragma unroll
            for (int off = 32; off; off >>= 1) {
#pragma unroll
                for (int d = 0; d < NED; ++d) {
                    sv[d] += __shfl_down(sv[d], off);
                    qv[d] += __shfl_down(qv[d], off);
                }
            }
            if (lane == 0) {
#pragma unroll
                for (int d = 0; d < NED; ++d) {
                    atomicAdd(&lsum[g0 * NED + d], sv[d]);
                    atomicAdd(&lsq[g0 * NED + d], qv[d]);
                }
                atomicAdd(&lcnt[g0], 64.f);
            }
        } else {
            atomicAdd(&lcnt[g], 1.0f);
#pragma unroll
            for (int d = 0; d < NED; ++d) {
                atomicAdd(&lsum[g * NED + d], a[d]);
                atomicAdd(&lsq[g * NED + d], a[d] * a[d]);
            }
        }
    }
    __syncthreads();
    for (int i = threadIdx.x; i < NG * NED; i += blockDim.x) {
        atomicAdd(&ssum[i], lsum[i]);
        atomicAdd(&ssq[i], lsq[i]);
    }
    for (int i = threadIdx.x; i < NG; i += blockDim.x) atomicAdd(&scnt[i], lcnt[i]);
}

__global__ void stats_fin(const float* __restrict__ ssum, const float* __restrict__ ssq,
                          const float* __restrict__ scnt,
                          float* __restrict__ mu, float* __restrict__ rstd) {
    int i = blockIdx.x * blockDim.x + threadIdx.x;
    if (i >= NG * NED) return;
    int g = i / NED;
    float c = fmaxf(scnt[g], 1.0f);
    float m = ssum[i] / c;
    float q = ssq[i] / c;
    float var = fmaxf(q - m * m, 0.f);
    mu[i] = m;
    rstd[i] = 1.0f / (sqrtf(var) + EPSF);
}

// ---------------- in-degree ----------------
__global__ void deg_kernel(const int* __restrict__ dst, float* __restrict__ deg) {
    int stride = gridDim.x * blockDim.x;
    for (int e = blockIdx.x * blockDim.x + threadIdx.x; e < NE; e += stride)
        atomicAdd(&deg[dst[e]], 1.0f);
}

// ---------------- lift MLP ----------------
__global__ __launch_bounds__(256) void lift_kernel(
    const float* __restrict__ x,
    const float* __restrict__ W1, const float* __restrict__ b1,
    const float* __restrict__ W2, const float* __restrict__ b2,
    float* __restrict__ v0, float* __restrict__ v, float* __restrict__ ldy) {
    __shared__ float sW1[NIN * NH];
    __shared__ __align__(16) float sW2[NH][NH];     // transposed: [j][k]
    __shared__ float sb1[NH], sb2[NH];
    for (int i = threadIdx.x; i < NIN * NH; i += blockDim.x) sW1[i] = W1[i];
    for (int i = threadIdx.x; i < NH * NH; i += blockDim.x) {
        int k = i >> 6, j = i & 63;
        sW2[j][k] = W2[i];
    }
    for (int i = threadIdx.x; i < NH; i += blockDim.x) { sb1[i] = b1[i]; sb2[i] = b2[i]; }
    __syncthreads();
    int stride = gridDim.x * blockDim.x;
    for (int n = blockIdx.x * blockDim.x + threadIdx.x; n < NN; n += stride) {
        float xr[NIN];
#pragma unroll
        for (int k = 0; k < NIN; ++k) xr[k] = x[(size_t)n * NIN + k];
        ldy[n] = xr[4];
        float h[NH];
#pragma unroll
        for (int j = 0; j < NH; ++j) {
            float acc = sb1[j];
#pragma unroll
            for (int k = 0; k < NIN; ++k) acc += xr[k] * sW1[k * NH + j];
            h[j] = fmaxf(acc, 0.f);
        }
#pragma unroll
        for (int j = 0; j < NH; ++j) {
            float acc = sb2[j];
#pragma unroll
            for (int k = 0; k < NH; k += 4) {
                float4 w = *(const float4*)&sW2[j][k];
                acc += h[k] * w.x + h[k + 1] * w.y + h[k + 2] * w.z + h[k + 3] * w.w;
            }
            v0[(size_t)n * NH + j] = acc;
            v[(size_t)n * NH + j] = acc;
        }
    }
}

// ---------------- shared micro-tile GEMM body ----------------
__device__ __forceinline__ void gemm_acc68(const float* __restrict__ Ab,
                                           const float* __restrict__ Wb,
                                           int K, int te, int tj, float acc[4][4]) {
#pragma unroll 4
    for (int k = 0; k < K; ++k) {
        float4 a = *(const float4*)(Ab + k * 68 + (te << 2));
        float4 b = *(const float4*)(Wb + (k << 6) + (tj << 2));
        acc[0][0] = fmaf(a.x, b.x, acc[0][0]);
        acc[0][1] = fmaf(a.x, b.y, acc[0][1]);
        acc[0][2] = fmaf(a.x, b.z, acc[0][2]);
        acc[0][3] = fmaf(a.x, b.w, acc[0][3]);
        acc[1][0] = fmaf(a.y, b.x, acc[1][0]);
        acc[1][1] = fmaf(a.y, b.y, acc[1][1]);
        acc[1][2] = fmaf(a.y, b.z, acc[1][2]);
        acc[1][3] = fmaf(a.y, b.w, acc[1][3]);
        acc[2][0] = fmaf(a.z, b.x, acc[2][0]);
        acc[2][1] = fmaf(a.z, b.y, acc[2][1]);
        acc[2][2] = fmaf(a.z, b.z, acc[2][2]);
        acc[2][3] = fmaf(a.z, b.w, acc[2][3]);
        acc[3][0] = fmaf(a.w, b.x, acc[3][0]);
        acc[3][1] = fmaf(a.w, b.y, acc[3][1]);
        acc[3][2] = fmaf(a.w, b.z, acc[3][2]);
        acc[3][3] = fmaf(a.w, b.w, acc[3][3]);
    }
}

// ---------------- U = v @ W0v + b0 (node-side layer-0) ----------------
__global__ __launch_bounds__(256, 4) void u_kernel(
    const float* __restrict__ v, const float* __restrict__ W0v,
    const float* __restrict__ b0, float* __restrict__ U) {
    __shared__ __align__(16) float Vt[64][68];   // [k][node]
    __shared__ __align__(16) float sW[64][64];   // [k][j]
    __shared__ float sb[64];
    const int tid = threadIdx.x;
    const int base = blockIdx.x * 64;
    const int te = tid >> 4, tj = tid & 15;

    {
        int r = tid >> 2;
        int kb = (tid & 3) << 4;
        int n = base + r;
        const float4* vrow = (const float4*)(v + (size_t)n * NH + kb);
#pragma unroll
        for (int q = 0; q < 4; ++q) {
            float4 f = (n < NN) ? vrow[q] : make_float4(0.f, 0.f, 0.f, 0.f);
            int k = kb + q * 4;
            Vt[k + 0][r] = f.x; Vt[k + 1][r] = f.y; Vt[k + 2][r] = f.z; Vt[k + 3][r] = f.w;
        }
    }
    for (int i4 = tid; i4 < 64 * 16; i4 += 256) {
        int k = i4 >> 4, c4 = i4 & 15;
        *(float4*)&sW[k][c4 * 4] = *(const float4*)(W0v + (size_t)k * 64 + c4 * 4);
    }
    if (tid < 64) sb[tid] = b0[tid];
    __syncthreads();

    float acc[4][4];
    {
        float b0_ = sb[tj * 4 + 0], b1_ = sb[tj * 4 + 1], b2_ = sb[tj * 4 + 2], b3_ = sb[tj * 4 + 3];
#pragma unroll
        for (int ee = 0; ee < 4; ++ee) { acc[ee][0] = b0_; acc[ee][1] = b1_; acc[ee][2] = b2_; acc[ee][3] = b3_; }
    }
    gemm_acc68(&Vt[0][0], &sW[0][0], 64, te, tj, acc);

#pragma unroll
    for (int ee = 0; ee < 4; ++ee) {
        int n = base + te * 4 + ee;
        if (n < NN)
            *(float4*)&U[(size_t)n * NH + tj * 4] =
                make_float4(acc[ee][0], acc[ee][1], acc[ee][2], acc[ee][3]);
    }
}

// ---------------- edge kernel: h0 = relu(U[src] + ea_n@W0e); h1 = relu(h0@W1+b1); scatter h1 ----------------
__global__ __launch_bounds__(256, 2) void edge_kernel(
    const int* __restrict__ ei, const float* __restrict__ ea, const int* __restrict__ batch,
    const float* __restrict__ mu, const float* __restrict__ rstd,
    const float* __restrict__ W0e, const float* __restrict__ W1, const float* __restrict__ b1,
    const float* __restrict__ U, float* __restrict__ nodesum) {
    __shared__ __align__(16) float Us[64][68];   // [edge][j]; reused for h1 staging
    __shared__ __align__(16) float H[64][68];    // [k][edge] for layer-1 A operand
    __shared__ __align__(16) float sW1[64][64];  // [k][j]
    __shared__ __align__(16) float sEa[NED][68]; // [d][edge]
    __shared__ __align__(16) float sWe[NED][64]; // [d][j]
    __shared__ float sb1[64];
    __shared__ int sDst[64];

    const int tid = threadIdx.x;
    const int base = blockIdx.x * 64;
    const int te = tid >> 4, tj = tid & 15;

    if (tid < 64) sDst[tid] = ei[NE + base + tid];
    // U[src] gather -> Us[edge][j]
    {
        int r = tid >> 2;
        int kb = (tid & 3) << 4;
        int s = ei[base + r];
        const float4* urow = (const float4*)(U + (size_t)s * NH + kb);
#pragma unroll
        for (int q = 0; q < 4; ++q)
            *(float4*)&Us[r][kb + q * 4] = urow[q];
    }
    // normalized edge attrs -> sEa[d][edge]
    for (int i = tid; i < 64 * NED; i += 256) {
        int e = i / NED, d = i - e * NED;
        int g = batch[ei[base + e]];
        float raw = ea[(size_t)(base + e) * NED + d];
        sEa[d][e] = (raw - mu[g * NED + d]) * rstd[g * NED + d];
    }
    // W0e (9x64), W1 (64x64), b1
    for (int i4 = tid; i4 < NED * 16; i4 += 256) {
        int k = i4 >> 4, c4 = i4 & 15;
        *(float4*)&sWe[k][c4 * 4] = *(const float4*)(W0e + (size_t)k * 64 + c4 * 4);
    }
    for (int i4 = tid; i4 < 64 * 16; i4 += 256) {
        int k = i4 >> 4, c4 = i4 & 15;
        *(float4*)&sW1[k][c4 * 4] = *(const float4*)(W1 + (size_t)k * 64 + c4 * 4);
    }
    if (tid < 64) sb1[tid] = b1[tid];
    __syncthreads();

    // ---- layer 0: acc = U[src] tile + ea_n @ W0e (K=9) ----
    float acc[4][4];
#pragma unroll
    for (int ee = 0; ee < 4; ++ee) {
        float4 u4 = *(const float4*)&Us[te * 4 + ee][tj * 4];
        acc[ee][0] = u4.x; acc[ee][1] = u4.y; acc[ee][2] = u4.z; acc[ee][3] = u4.w;
    }
    gemm_acc68(&sEa[0][0], &sWe[0][0], NED, te, tj, acc);

    // relu + transpose h0 -> H[j][edge]
#pragma unroll
    for (int jj = 0; jj < 4; ++jj) {
        float4 h4 = make_float4(fmaxf(acc[0][jj], 0.f), fmaxf(acc[1][jj], 0.f),
                                fmaxf(acc[2][jj], 0.f), fmaxf(acc[3][jj], 0.f));
        *(float4*)&H[tj * 4 + jj][te * 4] = h4;
    }
    __syncthreads();

    // ---- layer 1: h1 = relu(h0 @ W1 + b1), K=64 ----
    {
        float b0_ = sb1[tj * 4 + 0], b1_ = sb1[tj * 4 + 1], b2_ = sb1[tj * 4 + 2], b3_ = sb1[tj * 4 + 3];
#pragma unroll
        for (int ee = 0; ee < 4; ++ee) { acc[ee][0] = b0_; acc[ee][1] = b1_; acc[ee][2] = b2_; acc[ee][3] = b3_; }
    }
    gemm_acc68(&H[0][0], &sW1[0][0], 64, te, tj, acc);

    // relu -> Us[edge][j] for coalesced scatter (Us no longer read: all threads passed barrier)
#pragma unroll
    for (int ee = 0; ee < 4; ++ee) {
        float4 m4 = make_float4(fmaxf(acc[ee][0], 0.f), fmaxf(acc[ee][1], 0.f),
                                fmaxf(acc[ee][2], 0.f), fmaxf(acc[ee][3], 0.f));
        *(float4*)&Us[te * 4 + ee][tj * 4] = m4;
    }
    __syncthreads();

    // coalesced atomic scatter: one 256B row per edge
    {
        int wq = tid >> 6, lane = tid & 63;
#pragma unroll
        for (int r8 = 0; r8 < 16; ++r8) {
            int r = wq * 16 + r8;
            atomicAdd(&nodesum[(size_t)sDst[r] * NH + lane], Us[r][lane]);
        }
    }
}

// ---------------- node update: v = relu(v@Wself + bself + (S@W2)/cnt + b2[cnt>0] + v0) * gate ----------------
__global__ __launch_bounds__(256, 2) void update2_kernel(
    const float* __restrict__ Wself, const float* __restrict__ bself,
    const float* __restrict__ W2, const float* __restrict__ b2,
    const float* __restrict__ gWt, const float* __restrict__ gbt,
    const float* __restrict__ v0, const float* __restrict__ ldy,
    const float* __restrict__ deg, const float* __restrict__ nodesum,
    float* __restrict__ v) {
    __shared__ __align__(16) float Vt[64][68];   // [k][node]
    __shared__ __align__(16) float St[64][68];   // [k][node]
    __shared__ __align__(16) float sWs[64][64];
    __shared__ __align__(16) float sW2[64][64];
    __shared__ float sbs[64], sb2[64], sgw[64], sgb[64];
    const int tid = threadIdx.x;
    const int base = blockIdx.x * 64;
    const int te = tid >> 4, tj = tid & 15;

    {
        int r = tid >> 2;
        int kb = (tid & 3) << 4;
        int n = base + r;
        const float4* vrow = (const float4*)(v + (size_t)n * NH + kb);
        const float4* srow = (const float4*)(nodesum + (size_t)n * NH + kb);
#pragma unroll
        for (int q = 0; q < 4; ++q) {
            float4 f = (n < NN) ? vrow[q] : make_float4(0.f, 0.f, 0.f, 0.f);
            float4 g = (n < NN) ? srow[q] : make_float4(0.f, 0.f, 0.f, 0.f);
            int k = kb + q * 4;
            Vt[k + 0][r] = f.x; Vt[k + 1][r] = f.y; Vt[k + 2][r] = f.z; Vt[k + 3][r] = f.w;
            St[k + 0][r] = g.x; St[k + 1][r] = g.y; St[k + 2][r] = g.z; St[k + 3][r] = g.w;
        }
    }
    for (int i4 = tid; i4 < 64 * 16; i4 += 256) {
        int k = i4 >> 4, c4 = i4 & 15;
        *(float4*)&sWs[k][c4 * 4] = *(const float4*)(Wself + (size_t)k * 64 + c4 * 4);
        *(float4*)&sW2[k][c4 * 4] = *(const float4*)(W2 + (size_t)k * 64 + c4 * 4);
    }
    if (tid < 64) { sbs[tid] = bself[tid]; sb2[tid] = b2[tid]; sgw[tid] = gWt[tid]; sgb[tid] = gbt[tid]; }
    __syncthreads();

    float acc1[4][4], acc2[4][4];
    {
        float b0_ = sbs[tj * 4 + 0], b1_ = sbs[tj * 4 + 1], b2_ = sbs[tj * 4 + 2], b3_ = sbs[tj * 4 + 3];
#pragma unroll
        for (int ee = 0; ee < 4; ++ee) {
            acc1[ee][0] = b0_; acc1[ee][1] = b1_; acc1[ee][2] = b2_; acc1[ee][3] = b3_;
            acc2[ee][0] = 0.f; acc2[ee][1] = 0.f; acc2[ee][2] = 0.f; acc2[ee][3] = 0.f;
        }
    }
    gemm_acc68(&Vt[0][0], &sWs[0][0], 64, te, tj, acc1);
    gemm_acc68(&St[0][0], &sW2[0][0], 64, te, tj, acc2);

    float gw0 = sgw[tj * 4 + 0], gw1 = sgw[tj * 4 + 1], gw2 = sgw[tj * 4 + 2], gw3 = sgw[tj * 4 + 3];
    float gb0 = sgb[tj * 4 + 0], gb1 = sgb[tj * 4 + 1], gb2 = sgb[tj * 4 + 2], gb3 = sgb[tj * 4 + 3];
    float bb0 = sb2[tj * 4 + 0], bb1 = sb2[tj * 4 + 1], bb2 = sb2[tj * 4 + 2], bb3 = sb2[tj * 4 + 3];
#pragma unroll
    for (int ee = 0; ee < 4; ++ee) {
        int n = base + te * 4 + ee;
        if (n >= NN) continue;
        float cnt = deg[n];
        float has = (cnt > 0.5f) ? 1.f : 0.f;
        float dninv = has / fmaxf(cnt, 1.f);
        float ld = ldy[n];
        float4 v0r = *(const float4*)&v0[(size_t)n * NH + tj * 4];
        float z0 = acc1[ee][0] + acc2[ee][0] * dninv + bb0 * has + v0r.x;
        float z1 = acc1[ee][1] + acc2[ee][1] * dninv + bb1 * has + v0r.y;
        float z2 = acc1[ee][2] + acc2[ee][2] * dninv + bb2 * has + v0r.z;
        float z3 = acc1[ee][3] + acc2[ee][3] * dninv + bb3 * has + v0r.w;
        float g0 = 1.f / (1.f + expf(-(ld * gw0 + gb0)));
        float g1 = 1.f / (1.f + expf(-(ld * gw1 + gb1)));
        float g2 = 1.f / (1.f + expf(-(ld * gw2 + gb2)));
        float g3 = 1.f / (1.f + expf(-(ld * gw3 + gb3)));
        *(float4*)&v[(size_t)n * NH + tj * 4] =
            make_float4(fmaxf(z0, 0.f) * g0, fmaxf(z1, 0.f) * g1,
                        fmaxf(z2, 0.f) * g2, fmaxf(z3, 0.f) * g3);
    }
}

// ---------------- projection ----------------
__global__ __launch_bounds__(256) void proj_kernel(
    const float* __restrict__ v,
    const float* __restrict__ pW1, const float* __restrict__ pb1,
    const float* __restrict__ pW2, const float* __restrict__ pb2,
    float* __restrict__ out) {
    __shared__ __align__(16) float sW1[NH][NH];   // [j][k]
    __shared__ float sb1[NH];
    __shared__ float sW2[NH * NOUT];
    __shared__ float sb2[NOUT];
    for (int i = threadIdx.x; i < NH * NH; i += blockDim.x) {
        int k = i >> 6, j = i & 63;
        sW1[j][k] = pW1[i];
    }
    for (int i = threadIdx.x; i < NH; i += blockDim.x) sb1[i] = pb1[i];
    for (int i = threadIdx.x; i < NH * NOUT; i += blockDim.x) sW2[i] = pW2[i];
    for (int i = threadIdx.x; i < NOUT; i += blockDim.x) sb2[i] = pb2[i];
    __syncthreads();
    int stride = gridDim.x * blockDim.x;
    for (int n = blockIdx.x * blockDim.x + threadIdx.x; n < NN; n += stride) {
        float vr[NH];
        const float4* vp = (const float4*)(v + (size_t)n * NH);
#pragma unroll
        for (int q = 0; q < NH / 4; ++q) {
            float4 f = vp[q];
            vr[4 * q + 0] = f.x; vr[4 * q + 1] = f.y; vr[4 * q + 2] = f.z; vr[4 * q + 3] = f.w;
        }
        float o0 = sb2[0], o1 = sb2[1], o2 = sb2[2];
#pragma unroll
        for (int j = 0; j < NH; ++j) {
            float acc = sb1[j];
#pragma unroll
            for (int k = 0; k < NH; k += 4) {
                float4 w = *(const float4*)&sW1[j][k];
                acc += vr[k] * w.x + vr[k + 1] * w.y + vr[k + 2] * w.z + vr[k + 3] * w.w;
            }
            float h = fmaxf(acc, 0.f);
            o0 += h * sW2[j * NOUT + 0];
            o1 += h * sW2[j * NOUT + 1];
            o2 += h * sW2[j * NOUT + 2];
        }
        out[(size_t)n * NOUT + 0] = o0;
        out[(size_t)n * NOUT + 1] = o1;
        out[(size_t)n * NOUT + 2] = o2;
    }
}

extern "C" void kernel_launch(void* const* d_in, const int* in_sizes, int n_in,
                              void* d_out, int out_size, void* d_ws, size_t ws_size,
                              hipStream_t stream) {
    (void)in_sizes; (void)n_in; (void)out_size; (void)ws_size;
    const float* x     = (const float*)d_in[0];
    const int*   ei    = (const int*)d_in[1];
    const float* ea    = (const float*)d_in[2];
    const int*   batch = (const int*)d_in[3];
    const float* lW1   = (const float*)d_in[4];
    const float* lb1   = (const float*)d_in[5];
    const float* lW2   = (const float*)d_in[6];
    const float* lb2   = (const float*)d_in[7];
    const float* Wself = (const float*)d_in[8];
    const float* bself = (const float*)d_in[9];
    const float* mW0   = (const float*)d_in[10];
    const float* mb0   = (const float*)d_in[11];
    const float* mW1   = (const float*)d_in[12];
    const float* mb1   = (const float*)d_in[13];
    const float* mW2   = (const float*)d_in[14];
    const float* mb2   = (const float*)d_in[15];
    const float* gW    = (const float*)d_in[16];
    const float* gb    = (const float*)d_in[17];
    const float* pW1   = (const float*)d_in[18];
    const float* pb1   = (const float*)d_in[19];
    const float* pW2   = (const float*)d_in[20];
    const float* pb2   = (const float*)d_in[21];
    float* out = (float*)d_out;
    float* ws  = (float*)d_ws;

    float* nodesum = ws;                           // NN*NH
    float* deg  = nodesum + (size_t)NN * NH;       // NN
    float* ssum = deg + NN;                        // NG*NED
    float* ssq  = ssum + NG * NED;                 // NG*NED
    float* scnt = ssq + NG * NED;                  // NG
    float* v0   = scnt + NG;                       // NN*NH
    float* v    = v0 + (size_t)NN * NH;            // NN*NH
    float* ldy  = v + (size_t)NN * NH;             // NN
    float* mu   = ldy + NN;                        // NG*NED
    float* rstd = mu + NG * NED;                   // NG*NED
    float* U    = rstd + NG * NED;                 // NN*NH

    const int NBLK = (NN + 63) / 64;

    // zero deg + stats accumulators (contiguous)
    hipMemsetAsync(deg, 0, (size_t)(NN + 2 * NG * NED + NG) * sizeof(float), stream);

    stats_kernel<<<512, 256, 0, stream>>>(ei, ea, batch, ssum, ssq, scnt);
    stats_fin<<<3, 256, 0, stream>>>(ssum, ssq, scnt, mu, rstd);
    deg_kernel<<<2048, 256, 0, stream>>>(ei + NE, deg);
    lift_kernel<<<200, 256, 0, stream>>>(x, lW1, lb1, lW2, lb2, v0, v, ldy);

    for (int t = 0; t < NT; ++t) {
        const float* W0t = mW0 + (size_t)t * (NH + NED) * NH;
        hipMemsetAsync(nodesum, 0, (size_t)NN * NH * sizeof(float), stream);
        u_kernel<<<NBLK, 256, 0, stream>>>(v, W0t, mb0 + (size_t)t * NH, U);
        edge_kernel<<<NE / 64, 256, 0, stream>>>(
            ei, ea, batch, mu, rstd,
            W0t + (size_t)NH * NH,                      // W0e = rows 64..72
            mW1 + (size_t)t * NH * NH, mb1 + (size_t)t * NH,
            U, nodesum);
        update2_kernel<<<NBLK, 256, 0, stream>>>(
            Wself + (size_t)t * NH * NH, bself + (size_t)t * NH,
            mW2 + (size_t)t * NH * NH, mb2 + (size_t)t * NH,
            gW + (size_t)t * NH, gb + (size_t)t * NH,
            v0, ldy, deg, nodesum, v);
    }
    proj_kernel<<<200, 256, 0, stream>>>(v, pW1, pb1, pW2, pb2, out);
}

// Round 4
// 2559.955 us; speedup vs baseline: 11.2836x; 1.3523x over previous
//
#include <hip/hip_runtime.h>
#include <math.h>

#define NN 50000
#define NE 1600000
#define NG 64
#define NT 5
#define NH 64
#define NED 9
#define NIN 10
#define NOUT 3
#define EPSF 1e-6f

typedef __attribute__((ext_vector_type(8))) short s8v;    // 8 bf16 (4 VGPRs) MFMA frag
typedef __attribute__((ext_vector_type(4))) short s4v;    // 4 bf16 packed store
typedef __attribute__((ext_vector_type(4))) float f32x4;  // MFMA acc

__device__ __forceinline__ unsigned short f2bf(float f) {
    union { float f; unsigned int u; } v; v.f = f;
    unsigned int r = v.u + 0x7FFFu + ((v.u >> 16) & 1u);   // RNE
    return (unsigned short)(r >> 16);
}

// ---------------- per-graph edge stats (wave-uniform fast path) ----------------
__global__ void stats_kernel(const int* __restrict__ ei, const float* __restrict__ ea,
                             const int* __restrict__ batch,
                             float* __restrict__ ssum, float* __restrict__ ssq,
                             float* __restrict__ scnt) {
    __shared__ float lsum[NG * NED];
    __shared__ float lsq[NG * NED];
    __shared__ float lcnt[NG];
    for (int i = threadIdx.x; i < NG * NED; i += blockDim.x) { lsum[i] = 0.f; lsq[i] = 0.f; }
    for (int i = threadIdx.x; i < NG; i += blockDim.x) lcnt[i] = 0.f;
    __syncthreads();
    int lane = threadIdx.x & 63;
    int stride = gridDim.x * blockDim.x;
    for (int e = blockIdx.x * blockDim.x + threadIdx.x; e < NE; e += stride) {
        int s = ei[e];
        int g = batch[s];
        float a[NED];
#pragma unroll
        for (int d = 0; d < NED; ++d) a[d] = ea[(size_t)e * NED + d];
        int g0 = __builtin_amdgcn_readfirstlane(g);
        if (__all(g == g0)) {
            float sv[NED], qv[NED];
#pragma unroll
            for (int d = 0; d < NED; ++d) { sv[d] = a[d]; qv[d] = a[d] * a[d]; }
#pragma unroll
            for (int off = 32; off; off >>= 1) {
#pragma unroll
                for (int d = 0; d < NED; ++d) {
                    sv[d] += __shfl_down(sv[d], off);
                    qv[d] += __shfl_down(qv[d], off);
                }
            }
            if (lane == 0) {
#pragma unroll
                for (int d = 0; d < NED; ++d) {
                    atomicAdd(&lsum[g0 * NED + d], sv[d]);
                    atomicAdd(&lsq[g0 * NED + d], qv[d]);
                }
                atomicAdd(&lcnt[g0], 64.f);
            }
        } else {
            atomicAdd(&lcnt[g], 1.0f);
#pragma unroll
            for (int d = 0; d < NED; ++d) {
                atomicAdd(&lsum[g * NED + d], a[d]);
                atomicAdd(&lsq[g * NED + d], a[d] * a[d]);
            }
        }
    }
    __syncthreads();
    for (int i = threadIdx.x; i < NG * NED; i += blockDim.x) {
        atomicAdd(&ssum[i], lsum[i]);
        atomicAdd(&ssq[i], lsq[i]);
    }
    for (int i = threadIdx.x; i < NG; i += blockDim.x) atomicAdd(&scnt[i], lcnt[i]);
}

__global__ void stats_fin(const float* __restrict__ ssum, const float* __restrict__ ssq,
                          const float* __restrict__ scnt,
                          float* __restrict__ mu, float* __restrict__ rstd) {
    int i = blockIdx.x * blockDim.x + threadIdx.x;
    if (i >= NG * NED) return;
    int g = i / NED;
    float c = fmaxf(scnt[g], 1.0f);
    float m = ssum[i] / c;
    float q = ssq[i] / c;
    float var = fmaxf(q - m * m, 0.f);
    mu[i] = m;
    rstd[i] = 1.0f / (sqrtf(var) + EPSF);
}

// ---------------- in-degree ----------------
__global__ void deg_kernel(const int* __restrict__ dst, float* __restrict__ deg) {
    int stride = gridDim.x * blockDim.x;
    for (int e = blockIdx.x * blockDim.x + threadIdx.x; e < NE; e += stride)
        atomicAdd(&deg[dst[e]], 1.0f);
}

// ---------------- lift MLP ----------------
__global__ __launch_bounds__(256) void lift_kernel(
    const float* __restrict__ x,
    const float* __restrict__ W1, const float* __restrict__ b1,
    const float* __restrict__ W2, const float* __restrict__ b2,
    float* __restrict__ v0, float* __restrict__ v, float* __restrict__ ldy) {
    __shared__ float sW1[NIN * NH];
    __shared__ __align__(16) float sW2[NH][NH];     // transposed: [j][k]
    __shared__ float sb1[NH], sb2[NH];
    for (int i = threadIdx.x; i < NIN * NH; i += blockDim.x) sW1[i] = W1[i];
    for (int i = threadIdx.x; i < NH * NH; i += blockDim.x) {
        int k = i >> 6, j = i & 63;
        sW2[j][k] = W2[i];
    }
    for (int i = threadIdx.x; i < NH; i += blockDim.x) { sb1[i] = b1[i]; sb2[i] = b2[i]; }
    __syncthreads();
    int stride = gridDim.x * blockDim.x;
    for (int n = blockIdx.x * blockDim.x + threadIdx.x; n < NN; n += stride) {
        float xr[NIN];
#pragma unroll
        for (int k = 0; k < NIN; ++k) xr[k] = x[(size_t)n * NIN + k];
        ldy[n] = xr[4];
        float h[NH];
#pragma unroll
        for (int j = 0; j < NH; ++j) {
            float acc = sb1[j];
#pragma unroll
            for (int k = 0; k < NIN; ++k) acc += xr[k] * sW1[k * NH + j];
            h[j] = fmaxf(acc, 0.f);
        }
#pragma unroll
        for (int j = 0; j < NH; ++j) {
            float acc = sb2[j];
#pragma unroll
            for (int k = 0; k < NH; k += 4) {
                float4 w = *(const float4*)&sW2[j][k];
                acc += h[k] * w.x + h[k + 1] * w.y + h[k + 2] * w.z + h[k + 3] * w.w;
            }
            v0[(size_t)n * NH + j] = acc;
            v[(size_t)n * NH + j] = acc;
        }
    }
}

// ---------------- shared micro-tile GEMM body (fp32 paths) ----------------
__device__ __forceinline__ void gemm_acc68(const float* __restrict__ Ab,
                                           const float* __restrict__ Wb,
                                           int K, int te, int tj, float acc[4][4]) {
#pragma unroll 4
    for (int k = 0; k < K; ++k) {
        float4 a = *(const float4*)(Ab + k * 68 + (te << 2));
        float4 b = *(const float4*)(Wb + (k << 6) + (tj << 2));
        acc[0][0] = fmaf(a.x, b.x, acc[0][0]);
        acc[0][1] = fmaf(a.x, b.y, acc[0][1]);
        acc[0][2] = fmaf(a.x, b.z, acc[0][2]);
        acc[0][3] = fmaf(a.x, b.w, acc[0][3]);
        acc[1][0] = fmaf(a.y, b.x, acc[1][0]);
        acc[1][1] = fmaf(a.y, b.y, acc[1][1]);
        acc[1][2] = fmaf(a.y, b.z, acc[1][2]);
        acc[1][3] = fmaf(a.y, b.w, acc[1][3]);
        acc[2][0] = fmaf(a.z, b.x, acc[2][0]);
        acc[2][1] = fmaf(a.z, b.y, acc[2][1]);
        acc[2][2] = fmaf(a.z, b.z, acc[2][2]);
        acc[2][3] = fmaf(a.z, b.w, acc[2][3]);
        acc[3][0] = fmaf(a.w, b.x, acc[3][0]);
        acc[3][1] = fmaf(a.w, b.y, acc[3][1]);
        acc[3][2] = fmaf(a.w, b.z, acc[3][2]);
        acc[3][3] = fmaf(a.w, b.w, acc[3][3]);
    }
}

// ---------------- U = v @ W0v + b0 (node-side layer-0) ----------------
__global__ __launch_bounds__(256, 4) void u_kernel(
    const float* __restrict__ v, const float* __restrict__ W0v,
    const float* __restrict__ b0, float* __restrict__ U) {
    __shared__ __align__(16) float Vt[64][68];   // [k][node]
    __shared__ __align__(16) float sW[64][64];   // [k][j]
    __shared__ float sb[64];
    const int tid = threadIdx.x;
    const int base = blockIdx.x * 64;
    const int te = tid >> 4, tj = tid & 15;

    {
        int r = tid >> 2;
        int kb = (tid & 3) << 4;
        int n = base + r;
        const float4* vrow = (const float4*)(v + (size_t)n * NH + kb);
#pragma unroll
        for (int q = 0; q < 4; ++q) {
            float4 f = (n < NN) ? vrow[q] : make_float4(0.f, 0.f, 0.f, 0.f);
            int k = kb + q * 4;
            Vt[k + 0][r] = f.x; Vt[k + 1][r] = f.y; Vt[k + 2][r] = f.z; Vt[k + 3][r] = f.w;
        }
    }
    for (int i4 = tid; i4 < 64 * 16; i4 += 256) {
        int k = i4 >> 4, c4 = i4 & 15;
        *(float4*)&sW[k][c4 * 4] = *(const float4*)(W0v + (size_t)k * 64 + c4 * 4);
    }
    if (tid < 64) sb[tid] = b0[tid];
    __syncthreads();

    float acc[4][4];
    {
        float b0_ = sb[tj * 4 + 0], b1_ = sb[tj * 4 + 1], b2_ = sb[tj * 4 + 2], b3_ = sb[tj * 4 + 3];
#pragma unroll
        for (int ee = 0; ee < 4; ++ee) { acc[ee][0] = b0_; acc[ee][1] = b1_; acc[ee][2] = b2_; acc[ee][3] = b3_; }
    }
    gemm_acc68(&Vt[0][0], &sW[0][0], 64, te, tj, acc);

#pragma unroll
    for (int ee = 0; ee < 4; ++ee) {
        int n = base + te * 4 + ee;
        if (n < NN)
            *(float4*)&U[(size_t)n * NH + tj * 4] =
                make_float4(acc[ee][0], acc[ee][1], acc[ee][2], acc[ee][3]);
    }
}

// ---------------- edge kernel ----------------
// layer0 (fp32 VALU, K=9): h0 = relu(U[src] + ea_n@W0e)  -> bf16 LDS (MFMA A-layout, XOR-swizzled)
// layer1 (bf16 MFMA):      h1 = relu(h0@W1 + b1)         -> direct register atomic scatter
__global__ __launch_bounds__(256, 4) void edge_kernel(
    const int* __restrict__ ei, const float* __restrict__ ea, const int* __restrict__ batch,
    const float* __restrict__ mu, const float* __restrict__ rstd,
    const float* __restrict__ W0e, const float* __restrict__ W1, const float* __restrict__ b1,
    const float* __restrict__ U, float* __restrict__ nodesum) {
    __shared__ __align__(16) float Us[64][68];      // [edge][j] U gather (fp32)
    __shared__ __align__(16) float sEa[NED][68];    // [d][edge]
    __shared__ __align__(16) float sWe[NED][64];    // [d][j]
    __shared__ __align__(16) short h0bf[64 * 64];   // [e][k] bf16, swizzled
    __shared__ __align__(16) short W1bf[64 * 64];   // [j][k] bf16, swizzled
    __shared__ float sb1[64];
    __shared__ int sDst[64];

    const int tid = threadIdx.x;
    const int base = blockIdx.x * 64;
    const int te = tid >> 4, tj = tid & 15;

    if (tid < 64) { sDst[tid] = ei[NE + base + tid]; sb1[tid] = b1[tid]; }
    // U[src] gather -> Us[edge][j]
    {
        int r = tid >> 2;
        int kb = (tid & 3) << 4;
        int s = ei[base + r];
        const float4* urow = (const float4*)(U + (size_t)s * NH + kb);
#pragma unroll
        for (int q = 0; q < 4; ++q)
            *(float4*)&Us[r][kb + q * 4] = urow[q];
    }
    // normalized edge attrs -> sEa[d][edge]
    for (int i = tid; i < 64 * NED; i += 256) {
        int e = i / NED, d = i - e * NED;
        int g = batch[ei[base + e]];
        float raw = ea[(size_t)(base + e) * NED + d];
        sEa[d][e] = (raw - mu[g * NED + d]) * rstd[g * NED + d];
    }
    // W0e (9x64) fp32
    for (int i4 = tid; i4 < NED * 16; i4 += 256) {
        int k = i4 >> 4, c4 = i4 & 15;
        *(float4*)&sWe[k][c4 * 4] = *(const float4*)(W0e + (size_t)k * 64 + c4 * 4);
    }
    // W1 -> bf16 transposed [j][k] with XOR swizzle (byte ^= (j&7)<<4 within 128B row)
    for (int i4 = tid; i4 < 64 * 16; i4 += 256) {
        int k = i4 >> 4, j4 = (i4 & 15) * 4;
        float4 wv = *(const float4*)(W1 + (size_t)k * 64 + j4);
        unsigned short wb[4] = { f2bf(wv.x), f2bf(wv.y), f2bf(wv.z), f2bf(wv.w) };
        int kb = k * 2;
#pragma unroll
        for (int jj = 0; jj < 4; ++jj) {
            int row = j4 + jj;
            *(short*)((char*)W1bf + row * 128 + (kb ^ ((row & 7) << 4))) = (short)wb[jj];
        }
    }
    __syncthreads();

    // ---- layer 0: acc = U[src] tile + ea_n @ W0e (K=9), fp32 ----
    float acc0[4][4];
#pragma unroll
    for (int ee = 0; ee < 4; ++ee) {
        float4 u4 = *(const float4*)&Us[te * 4 + ee][tj * 4];
        acc0[ee][0] = u4.x; acc0[ee][1] = u4.y; acc0[ee][2] = u4.z; acc0[ee][3] = u4.w;
    }
    gemm_acc68(&sEa[0][0], &sWe[0][0], NED, te, tj, acc0);

    // relu -> h0bf[e][k] bf16, A-layout rows (e = row, k contiguous), swizzled
#pragma unroll
    for (int ee = 0; ee < 4; ++ee) {
        int row = te * 4 + ee;
        s4v p;
        p[0] = (short)f2bf(fmaxf(acc0[ee][0], 0.f));
        p[1] = (short)f2bf(fmaxf(acc0[ee][1], 0.f));
        p[2] = (short)f2bf(fmaxf(acc0[ee][2], 0.f));
        p[3] = (short)f2bf(fmaxf(acc0[ee][3], 0.f));
        *(s4v*)((char*)h0bf + row * 128 + ((tj * 8) ^ ((row & 7) << 4))) = p;
    }
    __syncthreads();

    // ---- layer 1: h1 = relu(h0 @ W1 + b1) via bf16 MFMA ----
    const int lane = tid & 63, w = tid >> 6;
    const int l15 = lane & 15, l4 = lane >> 4;
    f32x4 acc[4];
#pragma unroll
    for (int c = 0; c < 4; ++c) {
        float b = sb1[16 * c + l15];
        acc[c][0] = b; acc[c][1] = b; acc[c][2] = b; acc[c][3] = b;
    }
    {
        const int arow = 16 * w + l15;
        const char* abase = (const char*)h0bf + arow * 128;
        const int aswz = (arow & 7) << 4;
#pragma unroll
        for (int kc = 0; kc < 2; ++kc) {
            s8v af = *(const s8v*)(abase + ((16 * l4 + 64 * kc) ^ aswz));
#pragma unroll
            for (int c = 0; c < 4; ++c) {
                int brow = 16 * c + l15;
                s8v bf = *(const s8v*)((const char*)W1bf + brow * 128 +
                                       ((16 * l4 + 64 * kc) ^ ((brow & 7) << 4)));
                acc[c] = __builtin_amdgcn_mfma_f32_16x16x32_bf16(af, bf, acc[c], 0, 0, 0);
            }
        }
    }

    // ---- epilogue: relu + quarter-wave-coalesced atomic scatter from registers ----
    // D layout: row = 16w + 4*l4 + r, col = 16c + l15  [m89-verified mapping]
#pragma unroll
    for (int r = 0; r < 4; ++r) {
        int erow = 16 * w + 4 * l4 + r;
        float* dstrow = nodesum + (size_t)sDst[erow] * NH;
#pragma unroll
        for (int c = 0; c < 4; ++c) {
            atomicAdd(dstrow + 16 * c + l15, fmaxf(acc[c][r], 0.f));
        }
    }
}

// ---------------- node update: v = relu(v@Wself + bself + (S@W2)/cnt + b2[cnt>0] + v0) * gate ----------------
__global__ __launch_bounds__(256, 2) void update2_kernel(
    const float* __restrict__ Wself, const float* __restrict__ bself,
    const float* __restrict__ W2, const float* __restrict__ b2,
    const float* __restrict__ gWt, const float* __restrict__ gbt,
    const float* __restrict__ v0, const float* __restrict__ ldy,
    const float* __restrict__ deg, const float* __restrict__ nodesum,
    float* __restrict__ v) {
    __shared__ __align__(16) float Vt[64][68];   // [k][node]
    __shared__ __align__(16) float St[64][68];   // [k][node]
    __shared__ __align__(16) float sWs[64][64];
    __shared__ __align__(16) float sW2[64][64];
    __shared__ float sbs[64], sb2[64], sgw[64], sgb[64];
    const int tid = threadIdx.x;
    const int base = blockIdx.x * 64;
    const int te = tid >> 4, tj = tid & 15;

    {
        int r = tid >> 2;
        int kb = (tid & 3) << 4;
        int n = base + r;
        const float4* vrow = (const float4*)(v + (size_t)n * NH + kb);
        const float4* srow = (const float4*)(nodesum + (size_t)n * NH + kb);
#pragma unroll
        for (int q = 0; q < 4; ++q) {
            float4 f = (n < NN) ? vrow[q] : make_float4(0.f, 0.f, 0.f, 0.f);
            float4 g = (n < NN) ? srow[q] : make_float4(0.f, 0.f, 0.f, 0.f);
            int k = kb + q * 4;
            Vt[k + 0][r] = f.x; Vt[k + 1][r] = f.y; Vt[k + 2][r] = f.z; Vt[k + 3][r] = f.w;
            St[k + 0][r] = g.x; St[k + 1][r] = g.y; St[k + 2][r] = g.z; St[k + 3][r] = g.w;
        }
    }
    for (int i4 = tid; i4 < 64 * 16; i4 += 256) {
        int k = i4 >> 4, c4 = i4 & 15;
        *(float4*)&sWs[k][c4 * 4] = *(const float4*)(Wself + (size_t)k * 64 + c4 * 4);
        *(float4*)&sW2[k][c4 * 4] = *(const float4*)(W2 + (size_t)k * 64 + c4 * 4);
    }
    if (tid < 64) { sbs[tid] = bself[tid]; sb2[tid] = b2[tid]; sgw[tid] = gWt[tid]; sgb[tid] = gbt[tid]; }
    __syncthreads();

    float acc1[4][4], acc2[4][4];
    {
        float b0_ = sbs[tj * 4 + 0], b1_ = sbs[tj * 4 + 1], b2_ = sbs[tj * 4 + 2], b3_ = sbs[tj * 4 + 3];
#pragma unroll
        for (int ee = 0; ee < 4; ++ee) {
            acc1[ee][0] = b0_; acc1[ee][1] = b1_; acc1[ee][2] = b2_; acc1[ee][3] = b3_;
            acc2[ee][0] = 0.f; acc2[ee][1] = 0.f; acc2[ee][2] = 0.f; acc2[ee][3] = 0.f;
        }
    }
    gemm_acc68(&Vt[0][0], &sWs[0][0], 64, te, tj, acc1);
    gemm_acc68(&St[0][0], &sW2[0][0], 64, te, tj, acc2);

    float gw0 = sgw[tj * 4 + 0], gw1 = sgw[tj * 4 + 1], gw2 = sgw[tj * 4 + 2], gw3 = sgw[tj * 4 + 3];
    float gb0 = sgb[tj * 4 + 0], gb1 = sgb[tj * 4 + 1], gb2 = sgb[tj * 4 + 2], gb3 = sgb[tj * 4 + 3];
    float bb0 = sb2[tj * 4 + 0], bb1 = sb2[tj * 4 + 1], bb2 = sb2[tj * 4 + 2], bb3 = sb2[tj * 4 + 3];
#pragma unroll
    for (int ee = 0; ee < 4; ++ee) {
        int n = base + te * 4 + ee;
        if (n >= NN) continue;
        float cnt = deg[n];
        float has = (cnt > 0.5f) ? 1.f : 0.f;
        float dninv = has / fmaxf(cnt, 1.f);
        float ld = ldy[n];
        float4 v0r = *(const float4*)&v0[(size_t)n * NH + tj * 4];
        float z0 = acc1[ee][0] + acc2[ee][0] * dninv + bb0 * has + v0r.x;
        float z1 = acc1[ee][1] + acc2[ee][1] * dninv + bb1 * has + v0r.y;
        float z2 = acc1[ee][2] + acc2[ee][2] * dninv + bb2 * has + v0r.z;
        float z3 = acc1[ee][3] + acc2[ee][3] * dninv + bb3 * has + v0r.w;
        float g0 = 1.f / (1.f + expf(-(ld * gw0 + gb0)));
        float g1 = 1.f / (1.f + expf(-(ld * gw1 + gb1)));
        float g2 = 1.f / (1.f + expf(-(ld * gw2 + gb2)));
        float g3 = 1.f / (1.f + expf(-(ld * gw3 + gb3)));
        *(float4*)&v[(size_t)n * NH + tj * 4] =
            make_float4(fmaxf(z0, 0.f) * g0, fmaxf(z1, 0.f) * g1,
                        fmaxf(z2, 0.f) * g2, fmaxf(z3, 0.f) * g3);
    }
}

// ---------------- projection ----------------
__global__ __launch_bounds__(256) void proj_kernel(
    const float* __restrict__ v,
    const float* __restrict__ pW1, const float* __restrict__ pb1,
    const float* __restrict__ pW2, const float* __restrict__ pb2,
    float* __restrict__ out) {
    __shared__ __align__(16) float sW1[NH][NH];   // [j][k]
    __shared__ float sb1[NH];
    __shared__ float sW2[NH * NOUT];
    __shared__ float sb2[NOUT];
    for (int i = threadIdx.x; i < NH * NH; i += blockDim.x) {
        int k = i >> 6, j = i & 63;
        sW1[j][k] = pW1[i];
    }
    for (int i = threadIdx.x; i < NH; i += blockDim.x) sb1[i] = pb1[i];
    for (int i = threadIdx.x; i < NH * NOUT; i += blockDim.x) sW2[i] = pW2[i];
    for (int i = threadIdx.x; i < NOUT; i += blockDim.x) sb2[i] = pb2[i];
    __syncthreads();
    int stride = gridDim.x * blockDim.x;
    for (int n = blockIdx.x * blockDim.x + threadIdx.x; n < NN; n += stride) {
        float vr[NH];
        const float4* vp = (const float4*)(v + (size_t)n * NH);
#pragma unroll
        for (int q = 0; q < NH / 4; ++q) {
            float4 f = vp[q];
            vr[4 * q + 0] = f.x; vr[4 * q + 1] = f.y; vr[4 * q + 2] = f.z; vr[4 * q + 3] = f.w;
        }
        float o0 = sb2[0], o1 = sb2[1], o2 = sb2[2];
#pragma unroll
        for (int j = 0; j < NH; ++j) {
            float acc = sb1[j];
#pragma unroll
            for (int k = 0; k < NH; k += 4) {
                float4 w = *(const float4*)&sW1[j][k];
                acc += vr[k] * w.x + vr[k + 1] * w.y + vr[k + 2] * w.z + vr[k + 3] * w.w;
            }
            float h = fmaxf(acc, 0.f);
            o0 += h * sW2[j * NOUT + 0];
            o1 += h * sW2[j * NOUT + 1];
            o2 += h * sW2[j * NOUT + 2];
        }
        out[(size_t)n * NOUT + 0] = o0;
        out[(size_t)n * NOUT + 1] = o1;
        out[(size_t)n * NOUT + 2] = o2;
    }
}

extern "C" void kernel_launch(void* const* d_in, const int* in_sizes, int n_in,
                              void* d_out, int out_size, void* d_ws, size_t ws_size,
                              hipStream_t stream) {
    (void)in_sizes; (void)n_in; (void)out_size; (void)ws_size;
    const float* x     = (const float*)d_in[0];
    const int*   ei    = (const int*)d_in[1];
    const float* ea    = (const float*)d_in[2];
    const int*   batch = (const int*)d_in[3];
    const float* lW1   = (const float*)d_in[4];
    const float* lb1   = (const float*)d_in[5];
    const float* lW2   = (const float*)d_in[6];
    const float* lb2   = (const float*)d_in[7];
    const float* Wself = (const float*)d_in[8];
    const float* bself = (const float*)d_in[9];
    const float* mW0   = (const float*)d_in[10];
    const float* mb0   = (const float*)d_in[11];
    const float* mW1   = (const float*)d_in[12];
    const float* mb1   = (const float*)d_in[13];
    const float* mW2   = (const float*)d_in[14];
    const float* mb2   = (const float*)d_in[15];
    const float* gW    = (const float*)d_in[16];
    const float* gb    = (const float*)d_in[17];
    const float* pW1   = (const float*)d_in[18];
    const float* pb1   = (const float*)d_in[19];
    const float* pW2   = (const float*)d_in[20];
    const float* pb2   = (const float*)d_in[21];
    float* out = (float*)d_out;
    float* ws  = (float*)d_ws;

    float* nodesum = ws;                           // NN*NH
    float* deg  = nodesum + (size_t)NN * NH;       // NN
    float* ssum = deg + NN;                        // NG*NED
    float* ssq  = ssum + NG * NED;                 // NG*NED
    float* scnt = ssq + NG * NED;                  // NG
    float* v0   = scnt + NG;                       // NN*NH
    float* v    = v0 + (size_t)NN * NH;            // NN*NH
    float* ldy  = v + (size_t)NN * NH;             // NN
    float* mu   = ldy + NN;                        // NG*NED
    float* rstd = mu + NG * NED;                   // NG*NED
    float* U    = rstd + NG * NED;                 // NN*NH

    const int NBLK = (NN + 63) / 64;

    // zero deg + stats accumulators (contiguous)
    hipMemsetAsync(deg, 0, (size_t)(NN + 2 * NG * NED + NG) * sizeof(float), stream);

    stats_kernel<<<512, 256, 0, stream>>>(ei, ea, batch, ssum, ssq, scnt);
    stats_fin<<<3, 256, 0, stream>>>(ssum, ssq, scnt, mu, rstd);
    deg_kernel<<<2048, 256, 0, stream>>>(ei + NE, deg);
    lift_kernel<<<200, 256, 0, stream>>>(x, lW1, lb1, lW2, lb2, v0, v, ldy);

    for (int t = 0; t < NT; ++t) {
        const float* W0t = mW0 + (size_t)t * (NH + NED) * NH;
        hipMemsetAsync(nodesum, 0, (size_t)NN * NH * sizeof(float), stream);
        u_kernel<<<NBLK, 256, 0, stream>>>(v, W0t, mb0 + (size_t)t * NH, U);
        edge_kernel<<<NE / 64, 256, 0, stream>>>(
            ei, ea, batch, mu, rstd,
            W0t + (size_t)NH * NH,                      // W0e = rows 64..72
            mW1 + (size_t)t * NH * NH, mb1 + (size_t)t * NH,
            U, nodesum);
        update2_kernel<<<NBLK, 256, 0, stream>>>(
            Wself + (size_t)t * NH * NH, bself + (size_t)t * NH,
            mW2 + (size_t)t * NH * NH, mb2 + (size_t)t * NH,
            gW + (size_t)t * NH, gb + (size_t)t * NH,
            v0, ldy, deg, nodesum, v);
    }
    proj_kernel<<<200, 256, 0, stream>>>(v, pW1, pb1, pW2, pb2, out);
}

// Round 5
// 1610.903 us; speedup vs baseline: 17.9312x; 1.5891x over previous
//
#include <hip/hip_runtime.h>
#include <math.h>

#define NN 50000
#define NE 1600000
#define NG 64
#define NT 5
#define NH 64
#define NED 9
#define NIN 10
#define NOUT 3
#define EPSF 1e-6f

typedef __attribute__((ext_vector_type(8))) short s8v;    // 8 bf16 (4 VGPRs) MFMA frag
typedef __attribute__((ext_vector_type(4))) short s4v;    // 4 bf16 packed store
typedef __attribute__((ext_vector_type(4))) float f32x4;  // MFMA acc

__device__ __forceinline__ unsigned short f2bf(float f) {
    union { float f; unsigned int u; } v; v.f = f;
    unsigned int r = v.u + 0x7FFFu + ((v.u >> 16) & 1u);   // RNE
    return (unsigned short)(r >> 16);
}
__device__ __forceinline__ float bf2f(unsigned short b) {
    union { unsigned int u; float f; } v; v.u = ((unsigned int)b) << 16;
    return v.f;
}

// ---------------- per-graph edge stats (wave-uniform fast path) ----------------
__global__ void stats_kernel(const int* __restrict__ ei, const float* __restrict__ ea,
                             const int* __restrict__ batch,
                             float* __restrict__ ssum, float* __restrict__ ssq,
                             float* __restrict__ scnt) {
    __shared__ float lsum[NG * NED];
    __shared__ float lsq[NG * NED];
    __shared__ float lcnt[NG];
    for (int i = threadIdx.x; i < NG * NED; i += blockDim.x) { lsum[i] = 0.f; lsq[i] = 0.f; }
    for (int i = threadIdx.x; i < NG; i += blockDim.x) lcnt[i] = 0.f;
    __syncthreads();
    int lane = threadIdx.x & 63;
    int stride = gridDim.x * blockDim.x;
    for (int e = blockIdx.x * blockDim.x + threadIdx.x; e < NE; e += stride) {
        int s = ei[e];
        int g = batch[s];
        float a[NED];
#pragma unroll
        for (int d = 0; d < NED; ++d) a[d] = ea[(size_t)e * NED + d];
        int g0 = __builtin_amdgcn_readfirstlane(g);
        if (__all(g == g0)) {
            float sv[NED], qv[NED];
#pragma unroll
            for (int d = 0; d < NED; ++d) { sv[d] = a[d]; qv[d] = a[d] * a[d]; }
#pragma unroll
            for (int off = 32; off; off >>= 1) {
#pragma unroll
                for (int d = 0; d < NED; ++d) {
                    sv[d] += __shfl_down(sv[d], off);
                    qv[d] += __shfl_down(qv[d], off);
                }
            }
            if (lane == 0) {
#pragma unroll
                for (int d = 0; d < NED; ++d) {
                    atomicAdd(&lsum[g0 * NED + d], sv[d]);
                    atomicAdd(&lsq[g0 * NED + d], qv[d]);
                }
                atomicAdd(&lcnt[g0], 64.f);
            }
        } else {
            atomicAdd(&lcnt[g], 1.0f);
#pragma unroll
            for (int d = 0; d < NED; ++d) {
                atomicAdd(&lsum[g * NED + d], a[d]);
                atomicAdd(&lsq[g * NED + d], a[d] * a[d]);
            }
        }
    }
    __syncthreads();
    for (int i = threadIdx.x; i < NG * NED; i += blockDim.x) {
        atomicAdd(&ssum[i], lsum[i]);
        atomicAdd(&ssq[i], lsq[i]);
    }
    for (int i = threadIdx.x; i < NG; i += blockDim.x) atomicAdd(&scnt[i], lcnt[i]);
}

__global__ void stats_fin(const float* __restrict__ ssum, const float* __restrict__ ssq,
                          const float* __restrict__ scnt,
                          float* __restrict__ mu, float* __restrict__ rstd) {
    int i = blockIdx.x * blockDim.x + threadIdx.x;
    if (i >= NG * NED) return;
    int g = i / NED;
    float c = fmaxf(scnt[g], 1.0f);
    float m = ssum[i] / c;
    float q = ssq[i] / c;
    float var = fmaxf(q - m * m, 0.f);
    mu[i] = m;
    rstd[i] = 1.0f / (sqrtf(var) + EPSF);
}

// ---------------- integer in-degree ----------------
__global__ void degint_kernel(const int* __restrict__ dst, int* __restrict__ ecnt) {
    int stride = gridDim.x * blockDim.x;
    for (int e = blockIdx.x * blockDim.x + threadIdx.x; e < NE; e += stride)
        atomicAdd(&ecnt[dst[e]], 1);
}

// ---------------- exclusive scan of ecnt -> offs (3-phase) ----------------
__global__ void scan1_kernel(const int* __restrict__ ecnt, int* __restrict__ partial) {
    __shared__ int sm[256];
    int i = blockIdx.x * 256 + threadIdx.x;
    sm[threadIdx.x] = (i < NN) ? ecnt[i] : 0;
    __syncthreads();
    for (int off = 128; off; off >>= 1) {
        if (threadIdx.x < off) sm[threadIdx.x] += sm[threadIdx.x + off];
        __syncthreads();
    }
    if (threadIdx.x == 0) partial[blockIdx.x] = sm[0];
}
__global__ void scan2_kernel(int* __restrict__ partial, int nb) {
    __shared__ int sm[256];
    int t = threadIdx.x;
    sm[t] = (t < nb) ? partial[t] : 0;
    __syncthreads();
    for (int off = 1; off < 256; off <<= 1) {
        int v = (t >= off) ? sm[t - off] : 0;
        __syncthreads();
        sm[t] += v;
        __syncthreads();
    }
    if (t < nb) partial[t] = (t ? sm[t - 1] : 0);   // exclusive
}
__global__ void scan3_kernel(const int* __restrict__ ecnt, const int* __restrict__ partial,
                             int* __restrict__ offs) {
    __shared__ int sm[256];
    int b = blockIdx.x, t = threadIdx.x, i = b * 256 + t;
    int x = (i < NN) ? ecnt[i] : 0;
    sm[t] = x;
    __syncthreads();
    for (int off = 1; off < 256; off <<= 1) {
        int v = (t >= off) ? sm[t - off] : 0;
        __syncthreads();
        sm[t] += v;
        __syncthreads();
    }
    if (i < NN) offs[i] = sm[t] - x + partial[b];
}

// ---------------- counting-sort permutation by dst ----------------
__global__ void permute_kernel(const int* __restrict__ ei, const int* __restrict__ offs,
                               int* __restrict__ cursor, int* __restrict__ perm) {
    int stride = gridDim.x * blockDim.x;
    for (int e = blockIdx.x * blockDim.x + threadIdx.x; e < NE; e += stride) {
        int d = ei[NE + e];
        int pos = offs[d] + atomicAdd(&cursor[d], 1);
        perm[pos] = e;
    }
}

// ---------------- pack: srcPerm/dstPerm + normalized bf16 edge-attrs (SoA) ----------------
__global__ void pack_kernel(const int* __restrict__ perm, const int* __restrict__ ei,
                            const float* __restrict__ ea, const int* __restrict__ batch,
                            const float* __restrict__ mu, const float* __restrict__ rstd,
                            int* __restrict__ srcPerm, int* __restrict__ dstPerm,
                            unsigned short* __restrict__ eaN) {
    int stride = gridDim.x * blockDim.x;
    for (int p = blockIdx.x * blockDim.x + threadIdx.x; p < NE; p += stride) {
        int e = perm[p];
        int s = ei[e], d = ei[NE + e];
        int g = batch[s];
        srcPerm[p] = s;
        dstPerm[p] = d;
#pragma unroll
        for (int k = 0; k < NED; ++k) {
            float val = (ea[(size_t)e * NED + k] - mu[g * NED + k]) * rstd[g * NED + k];
            eaN[(size_t)k * NE + p] = f2bf(val);
        }
    }
}

// ---------------- lift MLP ----------------
__global__ __launch_bounds__(256) void lift_kernel(
    const float* __restrict__ x,
    const float* __restrict__ W1, const float* __restrict__ b1,
    const float* __restrict__ W2, const float* __restrict__ b2,
    float* __restrict__ v0, float* __restrict__ v, float* __restrict__ ldy) {
    __shared__ float sW1[NIN * NH];
    __shared__ __align__(16) float sW2[NH][NH];     // transposed: [j][k]
    __shared__ float sb1[NH], sb2[NH];
    for (int i = threadIdx.x; i < NIN * NH; i += blockDim.x) sW1[i] = W1[i];
    for (int i = threadIdx.x; i < NH * NH; i += blockDim.x) {
        int k = i >> 6, j = i & 63;
        sW2[j][k] = W2[i];
    }
    for (int i = threadIdx.x; i < NH; i += blockDim.x) { sb1[i] = b1[i]; sb2[i] = b2[i]; }
    __syncthreads();
    int stride = gridDim.x * blockDim.x;
    for (int n = blockIdx.x * blockDim.x + threadIdx.x; n < NN; n += stride) {
        float xr[NIN];
#pragma unroll
        for (int k = 0; k < NIN; ++k) xr[k] = x[(size_t)n * NIN + k];
        ldy[n] = xr[4];
        float h[NH];
#pragma unroll
        for (int j = 0; j < NH; ++j) {
            float acc = sb1[j];
#pragma unroll
            for (int k = 0; k < NIN; ++k) acc += xr[k] * sW1[k * NH + j];
            h[j] = fmaxf(acc, 0.f);
        }
#pragma unroll
        for (int j = 0; j < NH; ++j) {
            float acc = sb2[j];
#pragma unroll
            for (int k = 0; k < NH; k += 4) {
                float4 w = *(const float4*)&sW2[j][k];
                acc += h[k] * w.x + h[k + 1] * w.y + h[k + 2] * w.z + h[k + 3] * w.w;
            }
            v0[(size_t)n * NH + j] = acc;
            v[(size_t)n * NH + j] = acc;
        }
    }
}

// ---------------- shared micro-tile GEMM body (fp32 paths) ----------------
__device__ __forceinline__ void gemm_acc68(const float* __restrict__ Ab,
                                           const float* __restrict__ Wb,
                                           int K, int te, int tj, float acc[4][4]) {
#pragma unroll 4
    for (int k = 0; k < K; ++k) {
        float4 a = *(const float4*)(Ab + k * 68 + (te << 2));
        float4 b = *(const float4*)(Wb + (k << 6) + (tj << 2));
        acc[0][0] = fmaf(a.x, b.x, acc[0][0]);
        acc[0][1] = fmaf(a.x, b.y, acc[0][1]);
        acc[0][2] = fmaf(a.x, b.z, acc[0][2]);
        acc[0][3] = fmaf(a.x, b.w, acc[0][3]);
        acc[1][0] = fmaf(a.y, b.x, acc[1][0]);
        acc[1][1] = fmaf(a.y, b.y, acc[1][1]);
        acc[1][2] = fmaf(a.y, b.z, acc[1][2]);
        acc[1][3] = fmaf(a.y, b.w, acc[1][3]);
        acc[2][0] = fmaf(a.z, b.x, acc[2][0]);
        acc[2][1] = fmaf(a.z, b.y, acc[2][1]);
        acc[2][2] = fmaf(a.z, b.z, acc[2][2]);
        acc[2][3] = fmaf(a.z, b.w, acc[2][3]);
        acc[3][0] = fmaf(a.w, b.x, acc[3][0]);
        acc[3][1] = fmaf(a.w, b.y, acc[3][1]);
        acc[3][2] = fmaf(a.w, b.z, acc[3][2]);
        acc[3][3] = fmaf(a.w, b.w, acc[3][3]);
    }
}

// ---------------- U = v @ W0v + b0 (node-side layer-0) ----------------
__global__ __launch_bounds__(256, 4) void u_kernel(
    const float* __restrict__ v, const float* __restrict__ W0v,
    const float* __restrict__ b0, float* __restrict__ U) {
    __shared__ __align__(16) float Vt[64][68];   // [k][node]
    __shared__ __align__(16) float sW[64][64];   // [k][j]
    __shared__ float sb[64];
    const int tid = threadIdx.x;
    const int base = blockIdx.x * 64;
    const int te = tid >> 4, tj = tid & 15;

    {
        int r = tid >> 2;
        int kb = (tid & 3) << 4;
        int n = base + r;
        const float4* vrow = (const float4*)(v + (size_t)n * NH + kb);
#pragma unroll
        for (int q = 0; q < 4; ++q) {
            float4 f = (n < NN) ? vrow[q] : make_float4(0.f, 0.f, 0.f, 0.f);
            int k = kb + q * 4;
            Vt[k + 0][r] = f.x; Vt[k + 1][r] = f.y; Vt[k + 2][r] = f.z; Vt[k + 3][r] = f.w;
        }
    }
    for (int i4 = tid; i4 < 64 * 16; i4 += 256) {
        int k = i4 >> 4, c4 = i4 & 15;
        *(float4*)&sW[k][c4 * 4] = *(const float4*)(W0v + (size_t)k * 64 + c4 * 4);
    }
    if (tid < 64) sb[tid] = b0[tid];
    __syncthreads();

    float acc[4][4];
    {
        float b0_ = sb[tj * 4 + 0], b1_ = sb[tj * 4 + 1], b2_ = sb[tj * 4 + 2], b3_ = sb[tj * 4 + 3];
#pragma unroll
        for (int ee = 0; ee < 4; ++ee) { acc[ee][0] = b0_; acc[ee][1] = b1_; acc[ee][2] = b2_; acc[ee][3] = b3_; }
    }
    gemm_acc68(&Vt[0][0], &sW[0][0], 64, te, tj, acc);

#pragma unroll
    for (int ee = 0; ee < 4; ++ee) {
        int n = base + te * 4 + ee;
        if (n < NN)
            *(float4*)&U[(size_t)n * NH + tj * 4] =
                make_float4(acc[ee][0], acc[ee][1], acc[ee][2], acc[ee][3]);
    }
}

// ---------------- edge kernel (dst-sorted) ----------------
// layer0 (fp32 VALU, K=9): h0 = relu(U[src] + ea_n@W0e)  -> bf16 LDS (MFMA A-layout, swizzled)
// layer1 (bf16 MFMA):      h1 = relu(h0@W1 + b1)         -> LDS, per-wave segment reduce,
//                          one coalesced atomic row-add per distinct dst
__global__ __launch_bounds__(256, 4) void edge3_kernel(
    const int* __restrict__ srcPerm, const int* __restrict__ dstPerm,
    const unsigned short* __restrict__ eaN,
    const float* __restrict__ W0e, const float* __restrict__ W1, const float* __restrict__ b1,
    const float* __restrict__ U, float* __restrict__ nodesum) {
    __shared__ __align__(16) float Ubuf[64][68];    // U gather [edge][j]; reused for h1 [edge][j]
    __shared__ __align__(16) float sEa[NED][68];    // [d][edge]
    __shared__ __align__(16) float sWe[NED][64];    // [d][j]
    __shared__ __align__(16) short h0bf[64 * 64];   // [e][k] bf16, swizzled
    __shared__ __align__(16) short W1bf[64 * 64];   // [j][k] bf16, swizzled
    __shared__ float sb1[64];
    __shared__ int sDst[64];

    const int tid = threadIdx.x;
    const int base = blockIdx.x * 64;
    const int te = tid >> 4, tj = tid & 15;

    if (tid < 64) { sDst[tid] = dstPerm[base + tid]; sb1[tid] = b1[tid]; }
    // U[src] gather -> Ubuf[edge][j]
    {
        int r = tid >> 2;
        int kb = (tid & 3) << 4;
        int s = srcPerm[base + r];
        const float4* urow = (const float4*)(U + (size_t)s * NH + kb);
#pragma unroll
        for (int q = 0; q < 4; ++q)
            *(float4*)&Ubuf[r][kb + q * 4] = urow[q];
    }
    // normalized bf16 edge attrs (SoA, coalesced) -> sEa[d][edge] f32
    for (int i = tid; i < NED * 64; i += 256) {
        int d = i >> 6, c = i & 63;
        sEa[d][c] = bf2f(eaN[(size_t)d * NE + base + c]);
    }
    // W0e (9x64) fp32
    for (int i4 = tid; i4 < NED * 16; i4 += 256) {
        int k = i4 >> 4, c4 = i4 & 15;
        *(float4*)&sWe[k][c4 * 4] = *(const float4*)(W0e + (size_t)k * 64 + c4 * 4);
    }
    // W1 -> bf16 transposed [j][k] with XOR swizzle
    for (int i4 = tid; i4 < 64 * 16; i4 += 256) {
        int k = i4 >> 4, j4 = (i4 & 15) * 4;
        float4 wv = *(const float4*)(W1 + (size_t)k * 64 + j4);
        unsigned short wb[4] = { f2bf(wv.x), f2bf(wv.y), f2bf(wv.z), f2bf(wv.w) };
        int kb = k * 2;
#pragma unroll
        for (int jj = 0; jj < 4; ++jj) {
            int row = j4 + jj;
            *(short*)((char*)W1bf + row * 128 + (kb ^ ((row & 7) << 4))) = (short)wb[jj];
        }
    }
    __syncthreads();

    // ---- layer 0: acc = U[src] tile + ea_n @ W0e (K=9), fp32 ----
    float acc0[4][4];
#pragma unroll
    for (int ee = 0; ee < 4; ++ee) {
        float4 u4 = *(const float4*)&Ubuf[te * 4 + ee][tj * 4];
        acc0[ee][0] = u4.x; acc0[ee][1] = u4.y; acc0[ee][2] = u4.z; acc0[ee][3] = u4.w;
    }
    gemm_acc68(&sEa[0][0], &sWe[0][0], NED, te, tj, acc0);

    // relu -> h0bf[e][k] bf16, swizzled
#pragma unroll
    for (int ee = 0; ee < 4; ++ee) {
        int row = te * 4 + ee;
        s4v p;
        p[0] = (short)f2bf(fmaxf(acc0[ee][0], 0.f));
        p[1] = (short)f2bf(fmaxf(acc0[ee][1], 0.f));
        p[2] = (short)f2bf(fmaxf(acc0[ee][2], 0.f));
        p[3] = (short)f2bf(fmaxf(acc0[ee][3], 0.f));
        *(s4v*)((char*)h0bf + row * 128 + ((tj * 8) ^ ((row & 7) << 4))) = p;
    }
    __syncthreads();

    // ---- layer 1: h1 = relu(h0 @ W1 + b1) via bf16 MFMA ----
    const int lane = tid & 63, w = tid >> 6;
    const int l15 = lane & 15, l4 = lane >> 4;
    f32x4 acc[4];
#pragma unroll
    for (int c = 0; c < 4; ++c) {
        float b = sb1[16 * c + l15];
        acc[c][0] = b; acc[c][1] = b; acc[c][2] = b; acc[c][3] = b;
    }
    {
        const int arow = 16 * w + l15;
        const char* abase = (const char*)h0bf + arow * 128;
        const int aswz = (arow & 7) << 4;
#pragma unroll
        for (int kc = 0; kc < 2; ++kc) {
            s8v af = *(const s8v*)(abase + ((16 * l4 + 64 * kc) ^ aswz));
#pragma unroll
            for (int c = 0; c < 4; ++c) {
                int brow = 16 * c + l15;
                s8v bf = *(const s8v*)((const char*)W1bf + brow * 128 +
                                       ((16 * l4 + 64 * kc) ^ ((brow & 7) << 4)));
                acc[c] = __builtin_amdgcn_mfma_f32_16x16x32_bf16(af, bf, acc[c], 0, 0, 0);
            }
        }
    }

    // relu(h1) -> Ubuf[edge][j]  (D layout: row = 16w + 4*l4 + r, col = 16c + l15)
#pragma unroll
    for (int r = 0; r < 4; ++r) {
        int erow = 16 * w + 4 * l4 + r;
#pragma unroll
        for (int c = 0; c < 4; ++c)
            Ubuf[erow][16 * c + l15] = fmaxf(acc[c][r], 0.f);
    }
    __syncthreads();

    // ---- per-wave segment reduce over 16 dst-sorted edges, flush per distinct dst ----
    {
        int c = tid & 63;
        int r0 = 16 * w;
        int cur = sDst[r0];
        float a = Ubuf[r0][c];
#pragma unroll
        for (int i = 1; i < 16; ++i) {
            int d = sDst[r0 + i];            // wave-uniform
            float hv = Ubuf[r0 + i][c];
            if (d != cur) {
                atomicAdd(&nodesum[(size_t)cur * NH + c], a);
                cur = d;
                a = hv;
            } else {
                a += hv;
            }
        }
        atomicAdd(&nodesum[(size_t)cur * NH + c], a);
    }
}

// ---------------- node update ----------------
__global__ __launch_bounds__(256, 2) void update3_kernel(
    const float* __restrict__ Wself, const float* __restrict__ bself,
    const float* __restrict__ W2, const float* __restrict__ b2,
    const float* __restrict__ gWt, const float* __restrict__ gbt,
    const float* __restrict__ v0, const float* __restrict__ ldy,
    const int* __restrict__ ecnt, const float* __restrict__ nodesum,
    float* __restrict__ v) {
    __shared__ __align__(16) float Vt[64][68];   // [k][node]
    __shared__ __align__(16) float St[64][68];   // [k][node]
    __shared__ __align__(16) float sWs[64][64];
    __shared__ __align__(16) float sW2[64][64];
    __shared__ float sbs[64], sb2[64], sgw[64], sgb[64];
    const int tid = threadIdx.x;
    const int base = blockIdx.x * 64;
    const int te = tid >> 4, tj = tid & 15;

    {
        int r = tid >> 2;
        int kb = (tid & 3) << 4;
        int n = base + r;
        const float4* vrow = (const float4*)(v + (size_t)n * NH + kb);
        const float4* srow = (const float4*)(nodesum + (size_t)n * NH + kb);
#pragma unroll
        for (int q = 0; q < 4; ++q) {
            float4 f = (n < NN) ? vrow[q] : make_float4(0.f, 0.f, 0.f, 0.f);
            float4 g = (n < NN) ? srow[q] : make_float4(0.f, 0.f, 0.f, 0.f);
            int k = kb + q * 4;
            Vt[k + 0][r] = f.x; Vt[k + 1][r] = f.y; Vt[k + 2][r] = f.z; Vt[k + 3][r] = f.w;
            St[k + 0][r] = g.x; St[k + 1][r] = g.y; St[k + 2][r] = g.z; St[k + 3][r] = g.w;
        }
    }
    for (int i4 = tid; i4 < 64 * 16; i4 += 256) {
        int k = i4 >> 4, c4 = i4 & 15;
        *(float4*)&sWs[k][c4 * 4] = *(const float4*)(Wself + (size_t)k * 64 + c4 * 4);
        *(float4*)&sW2[k][c4 * 4] = *(const float4*)(W2 + (size_t)k * 64 + c4 * 4);
    }
    if (tid < 64) { sbs[tid] = bself[tid]; sb2[tid] = b2[tid]; sgw[tid] = gWt[tid]; sgb[tid] = gbt[tid]; }
    __syncthreads();

    float acc1[4][4], acc2[4][4];
    {
        float b0_ = sbs[tj * 4 + 0], b1_ = sbs[tj * 4 + 1], b2_ = sbs[tj * 4 + 2], b3_ = sbs[tj * 4 + 3];
#pragma unroll
        for (int ee = 0; ee < 4; ++ee) {
            acc1[ee][0] = b0_; acc1[ee][1] = b1_; acc1[ee][2] = b2_; acc1[ee][3] = b3_;
            acc2[ee][0] = 0.f; acc2[ee][1] = 0.f; acc2[ee][2] = 0.f; acc2[ee][3] = 0.f;
        }
    }
    gemm_acc68(&Vt[0][0], &sWs[0][0], 64, te, tj, acc1);
    gemm_acc68(&St[0][0], &sW2[0][0], 64, te, tj, acc2);

    float gw0 = sgw[tj * 4 + 0], gw1 = sgw[tj * 4 + 1], gw2 = sgw[tj * 4 + 2], gw3 = sgw[tj * 4 + 3];
    float gb0 = sgb[tj * 4 + 0], gb1 = sgb[tj * 4 + 1], gb2 = sgb[tj * 4 + 2], gb3 = sgb[tj * 4 + 3];
    float bb0 = sb2[tj * 4 + 0], bb1 = sb2[tj * 4 + 1], bb2 = sb2[tj * 4 + 2], bb3 = sb2[tj * 4 + 3];
#pragma unroll
    for (int ee = 0; ee < 4; ++ee) {
        int n = base + te * 4 + ee;
        if (n >= NN) continue;
        float cnt = (float)ecnt[n];
        float has = (cnt > 0.5f) ? 1.f : 0.f;
        float dninv = has / fmaxf(cnt, 1.f);
        float ld = ldy[n];
        float4 v0r = *(const float4*)&v0[(size_t)n * NH + tj * 4];
        float z0 = acc1[ee][0] + acc2[ee][0] * dninv + bb0 * has + v0r.x;
        float z1 = acc1[ee][1] + acc2[ee][1] * dninv + bb1 * has + v0r.y;
        float z2 = acc1[ee][2] + acc2[ee][2] * dninv + bb2 * has + v0r.z;
        float z3 = acc1[ee][3] + acc2[ee][3] * dninv + bb3 * has + v0r.w;
        float g0 = 1.f / (1.f + expf(-(ld * gw0 + gb0)));
        float g1 = 1.f / (1.f + expf(-(ld * gw1 + gb1)));
        float g2 = 1.f / (1.f + expf(-(ld * gw2 + gb2)));
        float g3 = 1.f / (1.f + expf(-(ld * gw3 + gb3)));
        *(float4*)&v[(size_t)n * NH + tj * 4] =
            make_float4(fmaxf(z0, 0.f) * g0, fmaxf(z1, 0.f) * g1,
                        fmaxf(z2, 0.f) * g2, fmaxf(z3, 0.f) * g3);
    }
}

// ---------------- projection ----------------
__global__ __launch_bounds__(256) void proj_kernel(
    const float* __restrict__ v,
    const float* __restrict__ pW1, const float* __restrict__ pb1,
    const float* __restrict__ pW2, const float* __restrict__ pb2,
    float* __restrict__ out) {
    __shared__ __align__(16) float sW1[NH][NH];   // [j][k]
    __shared__ float sb1[NH];
    __shared__ float sW2[NH * NOUT];
    __shared__ float sb2[NOUT];
    for (int i = threadIdx.x; i < NH * NH; i += blockDim.x) {
        int k = i >> 6, j = i & 63;
        sW1[j][k] = pW1[i];
    }
    for (int i = threadIdx.x; i < NH; i += blockDim.x) sb1[i] = pb1[i];
    for (int i = threadIdx.x; i < NH * NOUT; i += blockDim.x) sW2[i] = pW2[i];
    for (int i = threadIdx.x; i < NOUT; i += blockDim.x) sb2[i] = pb2[i];
    __syncthreads();
    int stride = gridDim.x * blockDim.x;
    for (int n = blockIdx.x * blockDim.x + threadIdx.x; n < NN; n += stride) {
        float vr[NH];
        const float4* vp = (const float4*)(v + (size_t)n * NH);
#pragma unroll
        for (int q = 0; q < NH / 4; ++q) {
            float4 f = vp[q];
            vr[4 * q + 0] = f.x; vr[4 * q + 1] = f.y; vr[4 * q + 2] = f.z; vr[4 * q + 3] = f.w;
        }
        float o0 = sb2[0], o1 = sb2[1], o2 = sb2[2];
#pragma unroll
        for (int j = 0; j < NH; ++j) {
            float acc = sb1[j];
#pragma unroll
            for (int k = 0; k < NH; k += 4) {
                float4 w = *(const float4*)&sW1[j][k];
                acc += vr[k] * w.x + vr[k + 1] * w.y + vr[k + 2] * w.z + vr[k + 3] * w.w;
            }
            float h = fmaxf(acc, 0.f);
            o0 += h * sW2[j * NOUT + 0];
            o1 += h * sW2[j * NOUT + 1];
            o2 += h * sW2[j * NOUT + 2];
        }
        out[(size_t)n * NOUT + 0] = o0;
        out[(size_t)n * NOUT + 1] = o1;
        out[(size_t)n * NOUT + 2] = o2;
    }
}

extern "C" void kernel_launch(void* const* d_in, const int* in_sizes, int n_in,
                              void* d_out, int out_size, void* d_ws, size_t ws_size,
                              hipStream_t stream) {
    (void)in_sizes; (void)n_in; (void)out_size; (void)ws_size;
    const float* x     = (const float*)d_in[0];
    const int*   ei    = (const int*)d_in[1];
    const float* ea    = (const float*)d_in[2];
    const int*   batch = (const int*)d_in[3];
    const float* lW1   = (const float*)d_in[4];
    const float* lb1   = (const float*)d_in[5];
    const float* lW2   = (const float*)d_in[6];
    const float* lb2   = (const float*)d_in[7];
    const float* Wself = (const float*)d_in[8];
    const float* bself = (const float*)d_in[9];
    const float* mW0   = (const float*)d_in[10];
    const float* mb0   = (const float*)d_in[11];
    const float* mW1   = (const float*)d_in[12];
    const float* mb1   = (const float*)d_in[13];
    const float* mW2   = (const float*)d_in[14];
    const float* mb2   = (const float*)d_in[15];
    const float* gW    = (const float*)d_in[16];
    const float* gb    = (const float*)d_in[17];
    const float* pW1   = (const float*)d_in[18];
    const float* pb1   = (const float*)d_in[19];
    const float* pW2   = (const float*)d_in[20];
    const float* pb2   = (const float*)d_in[21];
    float* out = (float*)d_out;
    float* ws  = (float*)d_ws;

    float* nodesum = ws;                              // NN*NH f32 (aliased as perm int[NE] pre-loop)
    float* v0   = nodesum + (size_t)NN * NH;          // NN*NH
    float* v    = v0 + (size_t)NN * NH;               // NN*NH
    float* U    = v + (size_t)NN * NH;                // NN*NH
    float* ldy  = U + (size_t)NN * NH;                // NN
    float* mu   = ldy + NN;                           // NG*NED
    float* rstd = mu + NG * NED;                      // NG*NED
    float* ssum = rstd + NG * NED;                    // NG*NED  (zeroed region start)
    float* ssq  = ssum + NG * NED;                    // NG*NED
    float* scnt = ssq + NG * NED;                     // NG
    int*   ecnt   = (int*)(scnt + NG);                // NN
    int*   cursor = ecnt + NN;                        // NN      (zeroed region end)
    int*   offs    = cursor + NN;                     // NN
    int*   partial = offs + NN;                       // 256
    int*   srcPerm = partial + 256;                   // NE
    int*   dstPerm = srcPerm + NE;                    // NE
    unsigned short* eaN = (unsigned short*)(dstPerm + NE);  // 9*NE bf16
    int*   perm = (int*)nodesum;                      // NE (alias, pre-loop only)

    const int NBLK = (NN + 63) / 64;       // 782
    const int SBLK = (NN + 255) / 256;     // 196

    // zero: ssum, ssq, scnt, ecnt, cursor (contiguous)
    hipMemsetAsync(ssum, 0, ((size_t)(2 * NG * NED + NG) + 2 * NN) * sizeof(float), stream);

    stats_kernel<<<512, 256, 0, stream>>>(ei, ea, batch, ssum, ssq, scnt);
    stats_fin<<<3, 256, 0, stream>>>(ssum, ssq, scnt, mu, rstd);
    degint_kernel<<<2048, 256, 0, stream>>>(ei + NE, ecnt);
    scan1_kernel<<<SBLK, 256, 0, stream>>>(ecnt, partial);
    scan2_kernel<<<1, 256, 0, stream>>>(partial, SBLK);
    scan3_kernel<<<SBLK, 256, 0, stream>>>(ecnt, partial, offs);
    permute_kernel<<<2048, 256, 0, stream>>>(ei, offs, cursor, perm);
    pack_kernel<<<2048, 256, 0, stream>>>(perm, ei, ea, batch, mu, rstd, srcPerm, dstPerm, eaN);
    lift_kernel<<<200, 256, 0, stream>>>(x, lW1, lb1, lW2, lb2, v0, v, ldy);

    for (int t = 0; t < NT; ++t) {
        const float* W0t = mW0 + (size_t)t * (NH + NED) * NH;
        hipMemsetAsync(nodesum, 0, (size_t)NN * NH * sizeof(float), stream);
        u_kernel<<<NBLK, 256, 0, stream>>>(v, W0t, mb0 + (size_t)t * NH, U);
        edge3_kernel<<<NE / 64, 256, 0, stream>>>(
            srcPerm, dstPerm, eaN,
            W0t + (size_t)NH * NH,                      // W0e = rows 64..72
            mW1 + (size_t)t * NH * NH, mb1 + (size_t)t * NH,
            U, nodesum);
        update3_kernel<<<NBLK, 256, 0, stream>>>(
            Wself + (size_t)t * NH * NH, bself + (size_t)t * NH,
            mW2 + (size_t)t * NH * NH, mb2 + (size_t)t * NH,
            gW + (size_t)t * NH, gb + (size_t)t * NH,
            v0, ldy, ecnt, nodesum, v);
    }
    proj_kernel<<<200, 256, 0, stream>>>(v, pW1, pb1, pW2, pb2, out);
}

// Round 6
// 1366.209 us; speedup vs baseline: 21.1428x; 1.1791x over previous
//
#include <hip/hip_runtime.h>
#include <math.h>

#define NN 50000
#define NE 1600000
#define NG 64
#define NT 5
#define NH 64
#define NED 9
#define NIN 10
#define NOUT 3
#define EPSF 1e-6f
#define NSUB (NE / 16)

typedef __attribute__((ext_vector_type(8))) short s8v;    // 8 bf16 (4 VGPRs) MFMA frag
typedef __attribute__((ext_vector_type(4))) short s4v;    // 4 bf16 packed store
typedef __attribute__((ext_vector_type(4))) float f32x4;  // MFMA acc

__device__ __forceinline__ unsigned short f2bf(float f) {
    union { float f; unsigned int u; } v; v.f = f;
    unsigned int r = v.u + 0x7FFFu + ((v.u >> 16) & 1u);   // RNE
    return (unsigned short)(r >> 16);
}
__device__ __forceinline__ float bf2f(unsigned short b) {
    union { unsigned int u; float f; } v; v.u = ((unsigned int)b) << 16;
    return v.f;
}

// ---------------- per-graph edge stats (wave-uniform fast path) + in-degree ----------------
__global__ void stats_kernel(const int* __restrict__ ei, const float* __restrict__ ea,
                             const int* __restrict__ batch,
                             float* __restrict__ ssum, float* __restrict__ ssq,
                             float* __restrict__ scnt, int* __restrict__ ecnt) {
    __shared__ float lsum[NG * NED];
    __shared__ float lsq[NG * NED];
    __shared__ float lcnt[NG];
    for (int i = threadIdx.x; i < NG * NED; i += blockDim.x) { lsum[i] = 0.f; lsq[i] = 0.f; }
    for (int i = threadIdx.x; i < NG; i += blockDim.x) lcnt[i] = 0.f;
    __syncthreads();
    int lane = threadIdx.x & 63;
    int stride = gridDim.x * blockDim.x;
    for (int e = blockIdx.x * blockDim.x + threadIdx.x; e < NE; e += stride) {
        int s = ei[e];
        int g = batch[s];
        atomicAdd(&ecnt[ei[NE + e]], 1);          // fused in-degree
        float a[NED];
#pragma unroll
        for (int d = 0; d < NED; ++d) a[d] = ea[(size_t)e * NED + d];
        int g0 = __builtin_amdgcn_readfirstlane(g);
        if (__all(g == g0)) {
            float sv[NED], qv[NED];
#pragma unroll
            for (int d = 0; d < NED; ++d) { sv[d] = a[d]; qv[d] = a[d] * a[d]; }
#pragma unroll
            for (int off = 32; off; off >>= 1) {
#pragma unroll
                for (int d = 0; d < NED; ++d) {
                    sv[d] += __shfl_down(sv[d], off);
                    qv[d] += __shfl_down(qv[d], off);
                }
            }
            if (lane == 0) {
#pragma unroll
                for (int d = 0; d < NED; ++d) {
                    atomicAdd(&lsum[g0 * NED + d], sv[d]);
                    atomicAdd(&lsq[g0 * NED + d], qv[d]);
                }
                atomicAdd(&lcnt[g0], 64.f);
            }
        } else {
            atomicAdd(&lcnt[g], 1.0f);
#pragma unroll
            for (int d = 0; d < NED; ++d) {
                atomicAdd(&lsum[g * NED + d], a[d]);
                atomicAdd(&lsq[g * NED + d], a[d] * a[d]);
            }
        }
    }
    __syncthreads();
    for (int i = threadIdx.x; i < NG * NED; i += blockDim.x) {
        atomicAdd(&ssum[i], lsum[i]);
        atomicAdd(&ssq[i], lsq[i]);
    }
    for (int i = threadIdx.x; i < NG; i += blockDim.x) atomicAdd(&scnt[i], lcnt[i]);
}

__global__ void stats_fin(const float* __restrict__ ssum, const float* __restrict__ ssq,
                          const float* __restrict__ scnt,
                          float* __restrict__ mu, float* __restrict__ rstd) {
    int i = blockIdx.x * blockDim.x + threadIdx.x;
    if (i >= NG * NED) return;
    int g = i / NED;
    float c = fmaxf(scnt[g], 1.0f);
    float m = ssum[i] / c;
    float q = ssq[i] / c;
    float var = fmaxf(q - m * m, 0.f);
    mu[i] = m;
    rstd[i] = 1.0f / (sqrtf(var) + EPSF);
}

// ---------------- exclusive scan of ecnt -> offs (3-phase) ----------------
__global__ void scan1_kernel(const int* __restrict__ ecnt, int* __restrict__ partial) {
    __shared__ int sm[256];
    int i = blockIdx.x * 256 + threadIdx.x;
    sm[threadIdx.x] = (i < NN) ? ecnt[i] : 0;
    __syncthreads();
    for (int off = 128; off; off >>= 1) {
        if (threadIdx.x < off) sm[threadIdx.x] += sm[threadIdx.x + off];
        __syncthreads();
    }
    if (threadIdx.x == 0) partial[blockIdx.x] = sm[0];
}
__global__ void scan2_kernel(int* __restrict__ partial, int nb) {
    __shared__ int sm[256];
    int t = threadIdx.x;
    sm[t] = (t < nb) ? partial[t] : 0;
    __syncthreads();
    for (int off = 1; off < 256; off <<= 1) {
        int v = (t >= off) ? sm[t - off] : 0;
        __syncthreads();
        sm[t] += v;
        __syncthreads();
    }
    if (t < nb) partial[t] = (t ? sm[t - 1] : 0);   // exclusive
}
__global__ void scan3_kernel(const int* __restrict__ ecnt, const int* __restrict__ partial,
                             int* __restrict__ offs) {
    __shared__ int sm[256];
    int b = blockIdx.x, t = threadIdx.x, i = b * 256 + t;
    int x = (i < NN) ? ecnt[i] : 0;
    sm[t] = x;
    __syncthreads();
    for (int off = 1; off < 256; off <<= 1) {
        int v = (t >= off) ? sm[t - off] : 0;
        __syncthreads();
        sm[t] += v;
        __syncthreads();
    }
    if (i < NN) offs[i] = sm[t] - x + partial[b];
}

// ---------------- counting-sort permutation by dst ----------------
__global__ void permute_kernel(const int* __restrict__ ei, const int* __restrict__ offs,
                               int* __restrict__ cursor, int* __restrict__ perm) {
    int stride = gridDim.x * blockDim.x;
    for (int e = blockIdx.x * blockDim.x + threadIdx.x; e < NE; e += stride) {
        int d = ei[NE + e];
        int pos = offs[d] + atomicAdd(&cursor[d], 1);
        perm[pos] = e;
    }
}

// ---------------- pack: srcPerm/dstPerm + normalized bf16 edge-attrs (SoA) ----------------
__global__ void pack_kernel(const int* __restrict__ perm, const int* __restrict__ ei,
                            const float* __restrict__ ea, const int* __restrict__ batch,
                            const float* __restrict__ mu, const float* __restrict__ rstd,
                            int* __restrict__ srcPerm, int* __restrict__ dstPerm,
                            unsigned short* __restrict__ eaN) {
    int stride = gridDim.x * blockDim.x;
    for (int p = blockIdx.x * blockDim.x + threadIdx.x; p < NE; p += stride) {
        int e = perm[p];
        int s = ei[e], d = ei[NE + e];
        int g = batch[s];
        srcPerm[p] = s;
        dstPerm[p] = d;
#pragma unroll
        for (int k = 0; k < NED; ++k) {
            float val = (ea[(size_t)e * NED + k] - mu[g * NED + k]) * rstd[g * NED + k];
            eaN[(size_t)k * NE + p] = f2bf(val);
        }
    }
}

// ---------------- lift MLP ----------------
__global__ __launch_bounds__(256) void lift_kernel(
    const float* __restrict__ x,
    const float* __restrict__ W1, const float* __restrict__ b1,
    const float* __restrict__ W2, const float* __restrict__ b2,
    float* __restrict__ v0, float* __restrict__ v, float* __restrict__ ldy) {
    __shared__ float sW1[NIN * NH];
    __shared__ __align__(16) float sW2[NH][NH];     // transposed: [j][k]
    __shared__ float sb1[NH], sb2[NH];
    for (int i = threadIdx.x; i < NIN * NH; i += blockDim.x) sW1[i] = W1[i];
    for (int i = threadIdx.x; i < NH * NH; i += blockDim.x) {
        int k = i >> 6, j = i & 63;
        sW2[j][k] = W2[i];
    }
    for (int i = threadIdx.x; i < NH; i += blockDim.x) { sb1[i] = b1[i]; sb2[i] = b2[i]; }
    __syncthreads();
    int stride = gridDim.x * blockDim.x;
    for (int n = blockIdx.x * blockDim.x + threadIdx.x; n < NN; n += stride) {
        float xr[NIN];
#pragma unroll
        for (int k = 0; k < NIN; ++k) xr[k] = x[(size_t)n * NIN + k];
        ldy[n] = xr[4];
        float h[NH];
#pragma unroll
        for (int j = 0; j < NH; ++j) {
            float acc = sb1[j];
#pragma unroll
            for (int k = 0; k < NIN; ++k) acc += xr[k] * sW1[k * NH + j];
            h[j] = fmaxf(acc, 0.f);
        }
#pragma unroll
        for (int j = 0; j < NH; ++j) {
            float acc = sb2[j];
#pragma unroll
            for (int k = 0; k < NH; k += 4) {
                float4 w = *(const float4*)&sW2[j][k];
                acc += h[k] * w.x + h[k + 1] * w.y + h[k + 2] * w.z + h[k + 3] * w.w;
            }
            v0[(size_t)n * NH + j] = acc;
            v[(size_t)n * NH + j] = acc;
        }
    }
}

// ---------------- shared micro-tile GEMM body (fp32 node kernels) ----------------
__device__ __forceinline__ void gemm_acc68(const float* __restrict__ Ab,
                                           const float* __restrict__ Wb,
                                           int K, int te, int tj, float acc[4][4]) {
#pragma unroll 4
    for (int k = 0; k < K; ++k) {
        float4 a = *(const float4*)(Ab + k * 68 + (te << 2));
        float4 b = *(const float4*)(Wb + (k << 6) + (tj << 2));
        acc[0][0] = fmaf(a.x, b.x, acc[0][0]);
        acc[0][1] = fmaf(a.x, b.y, acc[0][1]);
        acc[0][2] = fmaf(a.x, b.z, acc[0][2]);
        acc[0][3] = fmaf(a.x, b.w, acc[0][3]);
        acc[1][0] = fmaf(a.y, b.x, acc[1][0]);
        acc[1][1] = fmaf(a.y, b.y, acc[1][1]);
        acc[1][2] = fmaf(a.y, b.z, acc[1][2]);
        acc[1][3] = fmaf(a.y, b.w, acc[1][3]);
        acc[2][0] = fmaf(a.z, b.x, acc[2][0]);
        acc[2][1] = fmaf(a.z, b.y, acc[2][1]);
        acc[2][2] = fmaf(a.z, b.z, acc[2][2]);
        acc[2][3] = fmaf(a.z, b.w, acc[2][3]);
        acc[3][0] = fmaf(a.w, b.x, acc[3][0]);
        acc[3][1] = fmaf(a.w, b.y, acc[3][1]);
        acc[3][2] = fmaf(a.w, b.z, acc[3][2]);
        acc[3][3] = fmaf(a.w, b.w, acc[3][3]);
    }
}

// ---------------- U = v @ W0v + b0 (node-side layer-0) ----------------
__global__ __launch_bounds__(256, 4) void u_kernel(
    const float* __restrict__ v, const float* __restrict__ W0v,
    const float* __restrict__ b0, float* __restrict__ U) {
    __shared__ __align__(16) float Vt[64][68];   // [k][node]
    __shared__ __align__(16) float sW[64][64];   // [k][j]
    __shared__ float sb[64];
    const int tid = threadIdx.x;
    const int base = blockIdx.x * 64;
    const int te = tid >> 4, tj = tid & 15;

    {
        int r = tid >> 2;
        int kb = (tid & 3) << 4;
        int n = base + r;
        const float4* vrow = (const float4*)(v + (size_t)n * NH + kb);
#pragma unroll
        for (int q = 0; q < 4; ++q) {
            float4 f = (n < NN) ? vrow[q] : make_float4(0.f, 0.f, 0.f, 0.f);
            int k = kb + q * 4;
            Vt[k + 0][r] = f.x; Vt[k + 1][r] = f.y; Vt[k + 2][r] = f.z; Vt[k + 3][r] = f.w;
        }
    }
    for (int i4 = tid; i4 < 64 * 16; i4 += 256) {
        int k = i4 >> 4, c4 = i4 & 15;
        *(float4*)&sW[k][c4 * 4] = *(const float4*)(W0v + (size_t)k * 64 + c4 * 4);
    }
    if (tid < 64) sb[tid] = b0[tid];
    __syncthreads();

    float acc[4][4];
    {
        float b0_ = sb[tj * 4 + 0], b1_ = sb[tj * 4 + 1], b2_ = sb[tj * 4 + 2], b3_ = sb[tj * 4 + 3];
#pragma unroll
        for (int ee = 0; ee < 4; ++ee) { acc[ee][0] = b0_; acc[ee][1] = b1_; acc[ee][2] = b2_; acc[ee][3] = b3_; }
    }
    gemm_acc68(&Vt[0][0], &sW[0][0], 64, te, tj, acc);

#pragma unroll
    for (int ee = 0; ee < 4; ++ee) {
        int n = base + te * 4 + ee;
        if (n < NN)
            *(float4*)&U[(size_t)n * NH + tj * 4] =
                make_float4(acc[ee][0], acc[ee][1], acc[ee][2], acc[ee][3]);
    }
}

// ---------------- edge kernel: barrier-free wave-local, persistent weight frags ----------------
// Per wave, per 16-edge subtile:
//   layer0 (fp32 VALU, K=9): acc0 = U[src] (direct global) + ea_n @ W0e(LDS)
//   h0 -> bf16 wave-private LDS (swizzled A-layout)
//   layer1 (bf16 MFMA, W1 pre-staged as B-frags): h1 = relu(h0@W1 + b1)
//   reduce: single-dst fast path (reg + shfl_xor) or LDS segment reduce
__global__ __launch_bounds__(256, 4) void edge4_kernel(
    const int* __restrict__ srcPerm, const int* __restrict__ dstPerm,
    const unsigned short* __restrict__ eaN,
    const float* __restrict__ W0e, const float* __restrict__ W1, const float* __restrict__ b1,
    const float* __restrict__ U, float* __restrict__ nodesum) {
    __shared__ __align__(16) float sWe[NED][64];       // [d][j], staged once
    __shared__ __align__(16) short W1frag[8][64][8];   // [(kc*4+c)][lane][8] pre-built B-frags
    __shared__ __align__(16) short h0bf[4][16 * 64];   // per-wave, swizzled
    __shared__ __align__(16) float h1s[4][16 * 64];    // per-wave, col-swizzled
    __shared__ int sDstS[4][16];

    const int tid = threadIdx.x;
    const int lane = tid & 63, w = tid >> 6;
    const int l15 = lane & 15, l4 = lane >> 4;

    // ---- prologue staging (once per launch) ----
    for (int i4 = tid; i4 < NED * 16; i4 += 256) {
        int k = i4 >> 4, c4 = i4 & 15;
        *(float4*)&sWe[k][c4 * 4] = *(const float4*)(W0e + (size_t)k * 64 + c4 * 4);
    }
    for (int idx = tid; idx < 2 * 4 * 64; idx += 256) {
        int kc = idx >> 8, c = (idx >> 6) & 3, ln = idx & 63;
        int fl15 = ln & 15, fl4 = ln >> 4;
        int col = 16 * c + fl15;
        s8v frag;
#pragma unroll
        for (int j = 0; j < 8; ++j) {
            int k = kc * 32 + fl4 * 8 + j;
            frag[j] = (short)f2bf(W1[(size_t)k * 64 + col]);
        }
        *(s8v*)&W1frag[kc * 4 + c][ln][0] = frag;
    }
    float b1r[4];
#pragma unroll
    for (int c = 0; c < 4; ++c) b1r[c] = b1[16 * c + l15];
    __syncthreads();

    short* myh0 = h0bf[w];
    float* myh1 = h1s[w];
    int*   myd  = sDstS[w];
    const int gw = blockIdx.x * 4 + w;
    const int nw = gridDim.x * 4;

    for (int st = gw; st < NSUB; st += nw) {
        const int e16 = st * 16;
        if (lane < 16) myd[lane] = dstPerm[e16 + lane];

        // src ids + edge attrs for this lane's 4 edges (broadcast within l4 group)
        int4 s4 = *(const int4*)(srcPerm + e16 + 4 * l4);
        ushort4 eu[NED];
#pragma unroll
        for (int d = 0; d < NED; ++d)
            eu[d] = *(const ushort4*)(eaN + (size_t)d * NE + e16 + 4 * l4);

        // ---- layer 0: seed from U (direct global), K=9 fp32 ----
        float acc0[4][4];
        {
            const int* sp = (const int*)&s4;
#pragma unroll
            for (int ee = 0; ee < 4; ++ee) {
                float4 u4 = *(const float4*)(U + (size_t)sp[ee] * NH + 4 * l15);
                acc0[ee][0] = u4.x; acc0[ee][1] = u4.y; acc0[ee][2] = u4.z; acc0[ee][3] = u4.w;
            }
        }
#pragma unroll
        for (int d = 0; d < NED; ++d) {
            float4 wv = *(const float4*)&sWe[d][4 * l15];
            float a0 = bf2f(eu[d].x), a1 = bf2f(eu[d].y), a2 = bf2f(eu[d].z), a3 = bf2f(eu[d].w);
            acc0[0][0] = fmaf(a0, wv.x, acc0[0][0]); acc0[0][1] = fmaf(a0, wv.y, acc0[0][1]);
            acc0[0][2] = fmaf(a0, wv.z, acc0[0][2]); acc0[0][3] = fmaf(a0, wv.w, acc0[0][3]);
            acc0[1][0] = fmaf(a1, wv.x, acc0[1][0]); acc0[1][1] = fmaf(a1, wv.y, acc0[1][1]);
            acc0[1][2] = fmaf(a1, wv.z, acc0[1][2]); acc0[1][3] = fmaf(a1, wv.w, acc0[1][3]);
            acc0[2][0] = fmaf(a2, wv.x, acc0[2][0]); acc0[2][1] = fmaf(a2, wv.y, acc0[2][1]);
            acc0[2][2] = fmaf(a2, wv.z, acc0[2][2]); acc0[2][3] = fmaf(a2, wv.w, acc0[2][3]);
            acc0[3][0] = fmaf(a3, wv.x, acc0[3][0]); acc0[3][1] = fmaf(a3, wv.y, acc0[3][1]);
            acc0[3][2] = fmaf(a3, wv.z, acc0[3][2]); acc0[3][3] = fmaf(a3, wv.w, acc0[3][3]);
        }

        // relu -> h0 bf16 (rows = edges 4*l4+ee, cols 4*l15, XOR-swizzled)
#pragma unroll
        for (int ee = 0; ee < 4; ++ee) {
            int row = 4 * l4 + ee;
            s4v p;
            p[0] = (short)f2bf(fmaxf(acc0[ee][0], 0.f));
            p[1] = (short)f2bf(fmaxf(acc0[ee][1], 0.f));
            p[2] = (short)f2bf(fmaxf(acc0[ee][2], 0.f));
            p[3] = (short)f2bf(fmaxf(acc0[ee][3], 0.f));
            *(s4v*)((char*)myh0 + row * 128 + ((l15 * 8) ^ ((row & 7) << 4))) = p;
        }

        // ---- layer 1: h1 = h0 @ W1 + b1 via bf16 MFMA (wave-local, no barrier) ----
        f32x4 acc[4];
#pragma unroll
        for (int c = 0; c < 4; ++c) {
            float b = b1r[c];
            acc[c][0] = b; acc[c][1] = b; acc[c][2] = b; acc[c][3] = b;
        }
        {
            const char* abase = (const char*)myh0 + l15 * 128;
            const int aswz = (l15 & 7) << 4;
#pragma unroll
            for (int kc = 0; kc < 2; ++kc) {
                s8v af = *(const s8v*)(abase + ((l4 * 16 + kc * 64) ^ aswz));
#pragma unroll
                for (int c = 0; c < 4; ++c) {
                    s8v bf = *(const s8v*)&W1frag[kc * 4 + c][lane][0];
                    acc[c] = __builtin_amdgcn_mfma_f32_16x16x32_bf16(af, bf, acc[c], 0, 0, 0);
                }
            }
        }

        // ---- reduce + scatter (C layout: row = 4*l4 + r, col = 16c + l15) ----
        int dFirst = myd[0];
        int dLast = myd[15];
        if (dFirst == dLast) {
            // single-dst subtile: register reduce + cross-l4 shfl
#pragma unroll
            for (int c = 0; c < 4; ++c) {
                float vs = fmaxf(acc[c][0], 0.f) + fmaxf(acc[c][1], 0.f) +
                           fmaxf(acc[c][2], 0.f) + fmaxf(acc[c][3], 0.f);
                vs += __shfl_xor(vs, 16);
                vs += __shfl_xor(vs, 32);
                if (l4 == 0)
                    atomicAdd(&nodesum[(size_t)dFirst * NH + 16 * c + l15], vs);
            }
        } else {
            // LDS segment reduce (col-swizzled by l4 to kill bank aliasing)
#pragma unroll
            for (int r = 0; r < 4; ++r) {
                int row = 4 * l4 + r;
#pragma unroll
                for (int c = 0; c < 4; ++c)
                    myh1[row * 64 + ((16 * c + l15) ^ (l4 * 8))] = fmaxf(acc[c][r], 0.f);
            }
            int cur = dFirst;
            float a = myh1[lane];   // row 0, swz 0
#pragma unroll
            for (int i = 1; i < 16; ++i) {
                int dn = myd[i];
                float hv = myh1[i * 64 + (lane ^ ((i >> 2) * 8))];
                if (dn != cur) {
                    atomicAdd(&nodesum[(size_t)cur * NH + lane], a);
                    cur = dn;
                    a = hv;
                } else {
                    a += hv;
                }
            }
            atomicAdd(&nodesum[(size_t)cur * NH + lane], a);
        }
    }
}

// ---------------- node update ----------------
__global__ __launch_bounds__(256, 2) void update3_kernel(
    const float* __restrict__ Wself, const float* __restrict__ bself,
    const float* __restrict__ W2, const float* __restrict__ b2,
    const float* __restrict__ gWt, const float* __restrict__ gbt,
    const float* __restrict__ v0, const float* __restrict__ ldy,
    const int* __restrict__ ecnt, const float* __restrict__ nodesum,
    float* __restrict__ v) {
    __shared__ __align__(16) float Vt[64][68];   // [k][node]
    __shared__ __align__(16) float St[64][68];   // [k][node]
    __shared__ __align__(16) float sWs[64][64];
    __shared__ __align__(16) float sW2[64][64];
    __shared__ float sbs[64], sb2[64], sgw[64], sgb[64];
    const int tid = threadIdx.x;
    const int base = blockIdx.x * 64;
    const int te = tid >> 4, tj = tid & 15;

    {
        int r = tid >> 2;
        int kb = (tid & 3) << 4;
        int n = base + r;
        const float4* vrow = (const float4*)(v + (size_t)n * NH + kb);
        const float4* srow = (const float4*)(nodesum + (size_t)n * NH + kb);
#pragma unroll
        for (int q = 0; q < 4; ++q) {
            float4 f = (n < NN) ? vrow[q] : make_float4(0.f, 0.f, 0.f, 0.f);
            float4 g = (n < NN) ? srow[q] : make_float4(0.f, 0.f, 0.f, 0.f);
            int k = kb + q * 4;
            Vt[k + 0][r] = f.x; Vt[k + 1][r] = f.y; Vt[k + 2][r] = f.z; Vt[k + 3][r] = f.w;
            St[k + 0][r] = g.x; St[k + 1][r] = g.y; St[k + 2][r] = g.z; St[k + 3][r] = g.w;
        }
    }
    for (int i4 = tid; i4 < 64 * 16; i4 += 256) {
        int k = i4 >> 4, c4 = i4 & 15;
        *(float4*)&sWs[k][c4 * 4] = *(const float4*)(Wself + (size_t)k * 64 + c4 * 4);
        *(float4*)&sW2[k][c4 * 4] = *(const float4*)(W2 + (size_t)k * 64 + c4 * 4);
    }
    if (tid < 64) { sbs[tid] = bself[tid]; sb2[tid] = b2[tid]; sgw[tid] = gWt[tid]; sgb[tid] = gbt[tid]; }
    __syncthreads();

    float acc1[4][4], acc2[4][4];
    {
        float b0_ = sbs[tj * 4 + 0], b1_ = sbs[tj * 4 + 1], b2_ = sbs[tj * 4 + 2], b3_ = sbs[tj * 4 + 3];
#pragma unroll
        for (int ee = 0; ee < 4; ++ee) {
            acc1[ee][0] = b0_; acc1[ee][1] = b1_; acc1[ee][2] = b2_; acc1[ee][3] = b3_;
            acc2[ee][0] = 0.f; acc2[ee][1] = 0.f; acc2[ee][2] = 0.f; acc2[ee][3] = 0.f;
        }
    }
    gemm_acc68(&Vt[0][0], &sWs[0][0], 64, te, tj, acc1);
    gemm_acc68(&St[0][0], &sW2[0][0], 64, te, tj, acc2);

    float gw0 = sgw[tj * 4 + 0], gw1 = sgw[tj * 4 + 1], gw2 = sgw[tj * 4 + 2], gw3 = sgw[tj * 4 + 3];
    float gb0 = sgb[tj * 4 + 0], gb1 = sgb[tj * 4 + 1], gb2 = sgb[tj * 4 + 2], gb3 = sgb[tj * 4 + 3];
    float bb0 = sb2[tj * 4 + 0], bb1 = sb2[tj * 4 + 1], bb2 = sb2[tj * 4 + 2], bb3 = sb2[tj * 4 + 3];
#pragma unroll
    for (int ee = 0; ee < 4; ++ee) {
        int n = base + te * 4 + ee;
        if (n >= NN) continue;
        float cnt = (float)ecnt[n];
        float has = (cnt > 0.5f) ? 1.f : 0.f;
        float dninv = has / fmaxf(cnt, 1.f);
        float ld = ldy[n];
        float4 v0r = *(const float4*)&v0[(size_t)n * NH + tj * 4];
        float z0 = acc1[ee][0] + acc2[ee][0] * dninv + bb0 * has + v0r.x;
        float z1 = acc1[ee][1] + acc2[ee][1] * dninv + bb1 * has + v0r.y;
        float z2 = acc1[ee][2] + acc2[ee][2] * dninv + bb2 * has + v0r.z;
        float z3 = acc1[ee][3] + acc2[ee][3] * dninv + bb3 * has + v0r.w;
        float g0 = 1.f / (1.f + expf(-(ld * gw0 + gb0)));
        float g1 = 1.f / (1.f + expf(-(ld * gw1 + gb1)));
        float g2 = 1.f / (1.f + expf(-(ld * gw2 + gb2)));
        float g3 = 1.f / (1.f + expf(-(ld * gw3 + gb3)));
        *(float4*)&v[(size_t)n * NH + tj * 4] =
            make_float4(fmaxf(z0, 0.f) * g0, fmaxf(z1, 0.f) * g1,
                        fmaxf(z2, 0.f) * g2, fmaxf(z3, 0.f) * g3);
    }
}

// ---------------- projection ----------------
__global__ __launch_bounds__(256) void proj_kernel(
    const float* __restrict__ v,
    const float* __restrict__ pW1, const float* __restrict__ pb1,
    const float* __restrict__ pW2, const float* __restrict__ pb2,
    float* __restrict__ out) {
    __shared__ __align__(16) float sW1[NH][NH];   // [j][k]
    __shared__ float sb1[NH];
    __shared__ float sW2[NH * NOUT];
    __shared__ float sb2[NOUT];
    for (int i = threadIdx.x; i < NH * NH; i += blockDim.x) {
        int k = i >> 6, j = i & 63;
        sW1[j][k] = pW1[i];
    }
    for (int i = threadIdx.x; i < NH; i += blockDim.x) sb1[i] = pb1[i];
    for (int i = threadIdx.x; i < NH * NOUT; i += blockDim.x) sW2[i] = pW2[i];
    for (int i = threadIdx.x; i < NOUT; i += blockDim.x) sb2[i] = pb2[i];
    __syncthreads();
    int stride = gridDim.x * blockDim.x;
    for (int n = blockIdx.x * blockDim.x + threadIdx.x; n < NN; n += stride) {
        float vr[NH];
        const float4* vp = (const float4*)(v + (size_t)n * NH);
#pragma unroll
        for (int q = 0; q < NH / 4; ++q) {
            float4 f = vp[q];
            vr[4 * q + 0] = f.x; vr[4 * q + 1] = f.y; vr[4 * q + 2] = f.z; vr[4 * q + 3] = f.w;
        }
        float o0 = sb2[0], o1 = sb2[1], o2 = sb2[2];
#pragma unroll
        for (int j = 0; j < NH; ++j) {
            float acc = sb1[j];
#pragma unroll
            for (int k = 0; k < NH; k += 4) {
                float4 w = *(const float4*)&sW1[j][k];
                acc += vr[k] * w.x + vr[k + 1] * w.y + vr[k + 2] * w.z + vr[k + 3] * w.w;
            }
            float h = fmaxf(acc, 0.f);
            o0 += h * sW2[j * NOUT + 0];
            o1 += h * sW2[j * NOUT + 1];
            o2 += h * sW2[j * NOUT + 2];
        }
        out[(size_t)n * NOUT + 0] = o0;
        out[(size_t)n * NOUT + 1] = o1;
        out[(size_t)n * NOUT + 2] = o2;
    }
}

extern "C" void kernel_launch(void* const* d_in, const int* in_sizes, int n_in,
                              void* d_out, int out_size, void* d_ws, size_t ws_size,
                              hipStream_t stream) {
    (void)in_sizes; (void)n_in; (void)out_size; (void)ws_size;
    const float* x     = (const float*)d_in[0];
    const int*   ei    = (const int*)d_in[1];
    const float* ea    = (const float*)d_in[2];
    const int*   batch = (const int*)d_in[3];
    const float* lW1   = (const float*)d_in[4];
    const float* lb1   = (const float*)d_in[5];
    const float* lW2   = (const float*)d_in[6];
    const float* lb2   = (const float*)d_in[7];
    const float* Wself = (const float*)d_in[8];
    const float* bself = (const float*)d_in[9];
    const float* mW0   = (const float*)d_in[10];
    const float* mb0   = (const float*)d_in[11];
    const float* mW1   = (const float*)d_in[12];
    const float* mb1   = (const float*)d_in[13];
    const float* mW2   = (const float*)d_in[14];
    const float* mb2   = (const float*)d_in[15];
    const float* gW    = (const float*)d_in[16];
    const float* gb    = (const float*)d_in[17];
    const float* pW1   = (const float*)d_in[18];
    const float* pb1   = (const float*)d_in[19];
    const float* pW2   = (const float*)d_in[20];
    const float* pb2   = (const float*)d_in[21];
    float* out = (float*)d_out;
    float* ws  = (float*)d_ws;

    float* nodesum = ws;                              // NN*NH f32 (aliased as perm int[NE] pre-loop)
    float* v0   = nodesum + (size_t)NN * NH;          // NN*NH
    float* v    = v0 + (size_t)NN * NH;               // NN*NH
    float* U    = v + (size_t)NN * NH;                // NN*NH
    float* ldy  = U + (size_t)NN * NH;                // NN
    float* mu   = ldy + NN;                           // NG*NED
    float* rstd = mu + NG * NED;                      // NG*NED
    float* ssum = rstd + NG * NED;                    // NG*NED  (zeroed region start)
    float* ssq  = ssum + NG * NED;                    // NG*NED
    float* scnt = ssq + NG * NED;                     // NG
    int*   ecnt   = (int*)(scnt + NG);                // NN
    int*   cursor = ecnt + NN;                        // NN      (zeroed region end)
    int*   offs    = cursor + NN;                     // NN
    int*   partial = offs + NN;                       // 256
    int*   srcPerm = partial + 256;                   // NE
    int*   dstPerm = srcPerm + NE;                    // NE
    unsigned short* eaN = (unsigned short*)(dstPerm + NE);  // 9*NE bf16
    int*   perm = (int*)nodesum;                      // NE (alias, pre-loop only)

    const int NBLK = (NN + 63) / 64;       // 782
    const int SBLK = (NN + 255) / 256;     // 196

    // zero: ssum, ssq, scnt, ecnt, cursor (contiguous)
    hipMemsetAsync(ssum, 0, ((size_t)(2 * NG * NED + NG) + 2 * NN) * sizeof(float), stream);

    stats_kernel<<<512, 256, 0, stream>>>(ei, ea, batch, ssum, ssq, scnt, ecnt);
    stats_fin<<<3, 256, 0, stream>>>(ssum, ssq, scnt, mu, rstd);
    scan1_kernel<<<SBLK, 256, 0, stream>>>(ecnt, partial);
    scan2_kernel<<<1, 256, 0, stream>>>(partial, SBLK);
    scan3_kernel<<<SBLK, 256, 0, stream>>>(ecnt, partial, offs);
    permute_kernel<<<2048, 256, 0, stream>>>(ei, offs, cursor, perm);
    pack_kernel<<<2048, 256, 0, stream>>>(perm, ei, ea, batch, mu, rstd, srcPerm, dstPerm, eaN);
    lift_kernel<<<200, 256, 0, stream>>>(x, lW1, lb1, lW2, lb2, v0, v, ldy);

    for (int t = 0; t < NT; ++t) {
        const float* W0t = mW0 + (size_t)t * (NH + NED) * NH;
        hipMemsetAsync(nodesum, 0, (size_t)NN * NH * sizeof(float), stream);
        u_kernel<<<NBLK, 256, 0, stream>>>(v, W0t, mb0 + (size_t)t * NH, U);
        edge4_kernel<<<1024, 256, 0, stream>>>(
            srcPerm, dstPerm, eaN,
            W0t + (size_t)NH * NH,                      // W0e = rows 64..72
            mW1 + (size_t)t * NH * NH, mb1 + (size_t)t * NH,
            U, nodesum);
        update3_kernel<<<NBLK, 256, 0, stream>>>(
            Wself + (size_t)t * NH * NH, bself + (size_t)t * NH,
            mW2 + (size_t)t * NH * NH, mb2 + (size_t)t * NH,
            gW + (size_t)t * NH, gb + (size_t)t * NH,
            v0, ldy, ecnt, nodesum, v);
    }
    proj_kernel<<<200, 256, 0, stream>>>(v, pW1, pb1, pW2, pb2, out);
}